// Round 9
// baseline (723.719 us; speedup 1.0000x reference)
//
#include <hip/hip_runtime.h>
#include <hip/hip_bf16.h>

#define HD 128
#define NGAUSS 50
#define NLAYER 6
#define NGRAPH 16
#define NCLS 97
#define NTAB 2048
#define WMAX 12.0f

typedef __attribute__((ext_vector_type(8))) short bf16x8;
typedef __attribute__((ext_vector_type(4))) float f32x4;
typedef __attribute__((ext_vector_type(8))) ushort u16x8;
typedef __attribute__((ext_vector_type(4))) ushort u16x4;

__device__ __forceinline__ float ssp_f(float x) {
    float e = __expf(-fabsf(x));
    return fmaxf(x, 0.0f) + __logf(0.5f + 0.5f * e);
}
__device__ __forceinline__ ushort f2bf(float f) {   // RNE f32->bf16
    uint u = __float_as_uint(f);
    return (ushort)((u + 0x7FFFu + ((u >> 16) & 1u)) >> 16);
}
__device__ __forceinline__ float bf2f(ushort s) {
    return __uint_as_float(((uint)s) << 16);
}

// ================= CSR build =================
__global__ void hist_kernel(const int* __restrict__ col, int* __restrict__ deg, int E) {
    int e = blockIdx.x * blockDim.x + threadIdx.x;
    if (e < E) atomicAdd(&deg[col[e]], 1);
}

// 3-phase parallel scan (N <= 65536)
__global__ void scan1_kernel(const int* __restrict__ deg, int* __restrict__ rowp,
                             int* __restrict__ bsum, int N) {
    __shared__ int sm[256];
    const int t = threadIdx.x, i = blockIdx.x * 256 + t;
    int v = (i < N) ? deg[i] : 0;
    sm[t] = v;
    __syncthreads();
    for (int off = 1; off < 256; off <<= 1) {
        int x = sm[t];
        int a = (t >= off) ? sm[t - off] : 0;
        __syncthreads();
        sm[t] = x + a;
        __syncthreads();
    }
    if (i < N) rowp[i] = sm[t] - v;
    if (t == 255) bsum[blockIdx.x] = sm[255];
}
__global__ void scan2_kernel(const int* __restrict__ bsum, int* __restrict__ boff,
                             int NB, int* __restrict__ rowpN) {
    __shared__ int sm[256];
    const int t = threadIdx.x;
    int v = (t < NB) ? bsum[t] : 0;
    sm[t] = v;
    __syncthreads();
    for (int off = 1; off < 256; off <<= 1) {
        int x = sm[t];
        int a = (t >= off) ? sm[t - off] : 0;
        __syncthreads();
        sm[t] = x + a;
        __syncthreads();
    }
    if (t < NB) boff[t] = sm[t] - v;
    if (t == 255) *rowpN = sm[255];
}
__global__ void scan3_kernel(int* __restrict__ rowp, const int* __restrict__ boff,
                             int* __restrict__ cursor, int N) {
    int i = blockIdx.x * blockDim.x + threadIdx.x;
    if (i < N) {
        int r = rowp[i] + boff[i >> 8];
        rowp[i] = r;
        cursor[i] = r;
    }
}

// per-slot metadata (8 B): word0 = row | (tab_idx<<16); word1 = bf16{(1-f)*cenv} | bf16{f*cenv}<<16
__global__ void fill_kernel(const int* __restrict__ row, const int* __restrict__ col,
                            const float* __restrict__ pos, int* __restrict__ cursor,
                            uint2* __restrict__ meta, int E) {
    int e = blockIdx.x * blockDim.x + threadIdx.x;
    if (e >= E) return;
    int c = col[e], r = row[e];
    int slot = atomicAdd(&cursor[c], 1);
    float dx = pos[r*3+0] - pos[c*3+0];
    float dy = pos[r*3+1] - pos[c*3+1];
    float dz = pos[r*3+2] - pos[c*3+2];
    float w = sqrtf(dx*dx + dy*dy + dz*dz);
    float cenv = 0.5f * (cosf(w * 0.31415926535897931f) + 1.0f);
    const float invDW = (float)(NTAB - 1) / WMAX;
    float tt = w * invDW;
    int i = min((int)tt, NTAB - 1);
    float f = fminf(tt - (float)i, 1.0f);
    uint w0 = ((uint)r) | (((uint)i) << 16);
    uint w1 = ((uint)f2bf((1.0f - f) * cenv)) | (((uint)f2bf(f * cenv)) << 16);
    meta[slot] = make_uint2(w0, w1);
}

// ================= weight prep =================
__global__ void prep_kernel(const float* __restrict__ m1w, const float* __restrict__ c1w,
                            const float* __restrict__ c2w, const float* __restrict__ lw,
                            const float* __restrict__ l1w, const float* __restrict__ m2w,
                            ushort* __restrict__ m1T, ushort* __restrict__ nodeThi,
                            ushort* __restrict__ nodeTlo, ushort* __restrict__ m2T) {
    int idx = blockIdx.x * blockDim.x + threadIdx.x;
    const int S1 = 6*128*64, S2 = 19*128*128, S3 = 6*128*128;
    if (idx < S1) {
        int l = idx / 8192, r = idx % 8192, c = r / 64, k = r % 64;
        float v = (k < NGAUSS) ? m1w[(size_t)l*NGAUSS*128 + k*128 + c] : 0.0f;
        m1T[(size_t)l*8192 + c*64 + k] = f2bf(v);
    } else if (idx < S1 + S2) {
        int j = idx - S1;
        int m = j / 16384, r = j % 16384, c = r / 128, k = r % 128;
        const float* src;
        if (m < 6)       src = c1w + (size_t)m*16384;
        else if (m < 12) src = c2w + (size_t)(m-6)*16384;
        else if (m < 18) src = lw  + (size_t)(m-12)*16384;
        else             src = l1w;
        float v = src[k*128 + c];
        ushort hi = f2bf(v);
        nodeThi[(size_t)m*16384 + c*128 + k] = hi;
        nodeTlo[(size_t)m*16384 + c*128 + k] = f2bf(v - bf2f(hi));
    } else if (idx < S1 + S2 + S3) {
        int j = idx - S1 - S2;
        int l = j / 16384, r = j % 16384, c = r / 128, k = r % 128;
        m2T[(size_t)l*16384 + c*128 + k] = f2bf(m2w[(size_t)l*16384 + k*128 + c]);
    }
}

// ================= embedding =================
__global__ void embed_kernel(const float* __restrict__ x,
                             const float* __restrict__ emb_w, const float* __restrict__ emb_b,
                             float* __restrict__ h, int N) {
    int idx = blockIdx.x * blockDim.x + threadIdx.x;
    if (idx >= N * HD) return;
    int n = idx >> 7, t = idx & 127;
    float acc = emb_b[t];
    #pragma unroll
    for (int a = 0; a < 21; ++a) acc += x[n*21 + a] * emb_w[a*HD + t];
    h[idx] = acc;
}

// ================= filter table build (proven structure, 2048-pt grid) ======
__global__ __launch_bounds__(256, 2) void buildtab_kernel(
        const ushort* __restrict__ m1T_all, const ushort* __restrict__ m2T_all,
        const float* __restrict__ m1b_all, const float* __restrict__ m2b_all,
        float* __restrict__ T6) {
    __shared__ ushort A1[128 * 64];
    __shared__ ushort B1[128 * 64];
    __shared__ ushort U [128 * 128];
    char* A1b = (char*)A1;
    char* B1b = (char*)B1;
    char* Ub  = (char*)U;
    const int tid  = threadIdx.x;
    const int lane = tid & 63;
    const int wave = tid >> 6;
    const int l15  = lane & 15;
    const int kgrp = (lane >> 4) * 8;
    const int rbase = wave * 32;
    const int layer = blockIdx.x >> 4;
    const int mt    = blockIdx.x & 15;
    const ushort* m1T = m1T_all + (size_t)layer * 8192;
    const ushort* m2T = m2T_all + (size_t)layer * 16384;
    const float*  m1b = m1b_all + layer * HD;
    const float*  m2b = m2b_all + layer * HD;

    #pragma unroll
    for (int p = 0; p < 4; ++p) {
        int rr = p * 32 + (tid >> 3);
        int k8 = (tid & 7) * 8;
        u16x8 v = *reinterpret_cast<const u16x8*>(&m1T[(size_t)rr * 64 + k8]);
        *reinterpret_cast<u16x8*>(&B1b[rr*128 + ((2*k8) ^ ((rr & 7) << 4))]) = v;
    }

    float b1c[8], b2c[8];
    #pragma unroll
    for (int cb = 0; cb < 8; ++cb) { b1c[cb] = m1b[cb*16 + l15]; b2c[cb] = m2b[cb*16 + l15]; }

    const float step = 10.0f / 49.0f;
    const float coeff = -0.5f / (step * step);
    const float DW = WMAX / (float)(NTAB - 1);

    #pragma unroll
    for (int p = 0; p < 4; ++p) {
        int rr = p * 32 + (tid >> 3);
        int k8 = (tid & 7) * 8;
        float w = (float)(mt*128 + rr) * DW;
        u16x8 v;
        #pragma unroll
        for (int j = 0; j < 8; ++j) {
            int k = k8 + j;
            float d = w - (float)k * step;
            float g = (k < NGAUSS) ? __expf(coeff * d * d) : 0.0f;
            v[j] = f2bf(g);
        }
        *reinterpret_cast<u16x8*>(&A1b[rr*128 + ((2*k8) ^ ((rr & 7) << 4))]) = v;
    }
    __syncthreads();

    f32x4 acc1[2][8];
    #pragma unroll
    for (int i = 0; i < 2; ++i)
        #pragma unroll
        for (int j = 0; j < 8; ++j) { acc1[i][j].x=0.f; acc1[i][j].y=0.f; acc1[i][j].z=0.f; acc1[i][j].w=0.f; }
    #pragma unroll
    for (int ks = 0; ks < 2; ++ks) {
        int k = ks*32 + kgrp;
        bf16x8 af[2];
        #pragma unroll
        for (int rt = 0; rt < 2; ++rt) {
            int r = rbase + rt*16 + l15;
            af[rt] = *reinterpret_cast<const bf16x8*>(&A1b[r*128 + ((2*k) ^ ((r & 7) << 4))]);
        }
        #pragma unroll
        for (int cb = 0; cb < 8; ++cb) {
            int c = cb*16 + l15;
            bf16x8 bv = *reinterpret_cast<const bf16x8*>(&B1b[c*128 + ((2*k) ^ ((c & 7) << 4))]);
            acc1[0][cb] = __builtin_amdgcn_mfma_f32_16x16x32_bf16(af[0], bv, acc1[0][cb], 0, 0, 0);
            acc1[1][cb] = __builtin_amdgcn_mfma_f32_16x16x32_bf16(af[1], bv, acc1[1][cb], 0, 0, 0);
        }
    }
    #pragma unroll
    for (int rt = 0; rt < 2; ++rt) {
        #pragma unroll
        for (int cb = 0; cb < 8; ++cb) {
            int c = cb*16 + l15;
            #pragma unroll
            for (int i = 0; i < 4; ++i) {
                int rrow = rbase + rt*16 + (lane >> 4)*4 + i;
                ushort us = f2bf(ssp_f(acc1[rt][cb][i] + b1c[cb]));
                *reinterpret_cast<ushort*>(&Ub[rrow*256 + ((2*c) ^ ((rrow & 7) << 4))]) = us;
            }
        }
    }
    __syncthreads();

    f32x4 acc2[2][8];
    #pragma unroll
    for (int i = 0; i < 2; ++i)
        #pragma unroll
        for (int j = 0; j < 8; ++j) { acc2[i][j].x=0.f; acc2[i][j].y=0.f; acc2[i][j].z=0.f; acc2[i][j].w=0.f; }
    #pragma unroll
    for (int kh = 0; kh < 2; ++kh) {
        if (kh) __syncthreads();
        #pragma unroll
        for (int p = 0; p < 4; ++p) {
            int rr = p * 32 + (tid >> 3);
            int kk = (tid & 7) * 8;
            u16x8 v = *reinterpret_cast<const u16x8*>(&m2T[(size_t)rr*128 + kh*64 + kk]);
            *reinterpret_cast<u16x8*>(&A1b[rr*128 + ((2*kk) ^ ((rr & 7) << 4))]) = v;
        }
        __syncthreads();
        #pragma unroll
        for (int ks2 = 0; ks2 < 2; ++ks2) {
            int ku = kh*64 + ks2*32 + kgrp;
            int kb = ks2*32 + kgrp;
            bf16x8 af[2];
            #pragma unroll
            for (int rt = 0; rt < 2; ++rt) {
                int r = rbase + rt*16 + l15;
                af[rt] = *reinterpret_cast<const bf16x8*>(&Ub[r*256 + ((2*ku) ^ ((r & 7) << 4))]);
            }
            #pragma unroll
            for (int cb = 0; cb < 8; ++cb) {
                int c = cb*16 + l15;
                bf16x8 bv = *reinterpret_cast<const bf16x8*>(&A1b[c*128 + ((2*kb) ^ ((c & 7) << 4))]);
                acc2[0][cb] = __builtin_amdgcn_mfma_f32_16x16x32_bf16(af[0], bv, acc2[0][cb], 0, 0, 0);
                acc2[1][cb] = __builtin_amdgcn_mfma_f32_16x16x32_bf16(af[1], bv, acc2[1][cb], 0, 0, 0);
            }
        }
    }

    #pragma unroll
    for (int rt = 0; rt < 2; ++rt) {
        #pragma unroll
        for (int cb = 0; cb < 8; ++cb) {
            int c = cb*16 + l15;
            #pragma unroll
            for (int i = 0; i < 4; ++i) {
                int rrow = rbase + rt*16 + (lane >> 4)*4 + i;
                T6[((size_t)layer*NTAB + mt*128 + rrow) * HD + c] = acc2[rt][cb][i] + b2c[cb];
            }
        }
    }
}

// pack table rows i,i+1 as {bf16,bf16} in one u32
__global__ void packtab_kernel(const float* __restrict__ T6, uint* __restrict__ P6) {
    int idx = blockIdx.x * blockDim.x + threadIdx.x;
    if (idx >= 6 * NTAB * HD) return;
    int r = (idx >> 7) & (NTAB - 1);
    float v0 = T6[idx];
    float v1 = (r + 1 < NTAB) ? T6[idx + HD] : v0;
    P6[idx] = ((uint)f2bf(v0)) | (((uint)f2bf(v1)) << 16);
}

// ================= 64-row-tile GEMV (layer-0 c1 only): hxb = bf16(h @ (Bhi+Blo)) ====
__global__ __launch_bounds__(256) void gemv64_kernel(
        const float* __restrict__ A, const ushort* __restrict__ BThi,
        const ushort* __restrict__ BTlo, ushort* __restrict__ bdst, int mtiles) {
    __shared__ ushort A_[64 * 128];
    __shared__ ushort B_[128 * 128];
    char* Ab = (char*)A_;
    char* Bb = (char*)B_;
    const int tid  = threadIdx.x;
    const int lane = tid & 63;
    const int wave = tid >> 6;
    const int l15  = lane & 15;
    const int kgrp = (lane >> 4) * 8;
    const int rbase = wave * 16;

    for (int mt = blockIdx.x; mt < mtiles; mt += gridDim.x) {
        __syncthreads();
        #pragma unroll
        for (int p = 0; p < 8; ++p) {
            int rr = p * 8 + (tid >> 5);
            int k4 = (tid & 31) * 4;
            f32x4 v = *reinterpret_cast<const f32x4*>(&A[(size_t)(mt*64 + rr)*HD + k4]);
            u16x4 b;
            b.x = f2bf(v.x); b.y = f2bf(v.y); b.z = f2bf(v.z); b.w = f2bf(v.w);
            *reinterpret_cast<u16x4*>(&Ab[rr*256 + ((2*k4) ^ ((rr & 7) << 4))]) = b;
        }

        f32x4 acc[8];
        #pragma unroll
        for (int j = 0; j < 8; ++j) { acc[j].x=0.f; acc[j].y=0.f; acc[j].z=0.f; acc[j].w=0.f; }

        #pragma unroll
        for (int part = 0; part < 2; ++part) {
            const ushort* BT = part ? BTlo : BThi;
            __syncthreads();
            #pragma unroll
            for (int p = 0; p < 8; ++p) {
                int rr = p * 16 + (tid >> 4);
                int k8 = (tid & 15) * 8;
                u16x8 v = *reinterpret_cast<const u16x8*>(&BT[(size_t)rr*128 + k8]);
                *reinterpret_cast<u16x8*>(&Bb[rr*256 + ((2*k8) ^ ((rr & 7) << 4))]) = v;
            }
            __syncthreads();
            #pragma unroll
            for (int ks = 0; ks < 4; ++ks) {
                int k = ks*32 + kgrp;
                int r = rbase + l15;
                bf16x8 af = *reinterpret_cast<const bf16x8*>(&Ab[r*256 + ((2*k) ^ ((r & 7) << 4))]);
                #pragma unroll
                for (int cb = 0; cb < 8; ++cb) {
                    int c = cb*16 + l15;
                    bf16x8 bv = *reinterpret_cast<const bf16x8*>(&Bb[c*256 + ((2*k) ^ ((c & 7) << 4))]);
                    acc[cb] = __builtin_amdgcn_mfma_f32_16x16x32_bf16(af, bv, acc[cb], 0, 0, 0);
                }
            }
        }

        #pragma unroll
        for (int cb = 0; cb < 8; ++cb) {
            int c = cb*16 + l15;
            #pragma unroll
            for (int i = 0; i < 4; ++i) {
                int row = mt*64 + rbase + (lane >> 4)*4 + i;
                bdst[(size_t)row * HD + c] = f2bf(acc[cb][i]);
            }
        }
    }
}

// ================= fused node block (32-row tile, wave column-split, 3 GEMMs) =======
// Waves: (wave&1) = row half (16 rows), (wave>>1) = col half (4 cb = 64 cols).
// GEMM1: t = ssp(aggb @ (c2hi+c2lo) + c2b)
// GEMM2: hv = h + t @ (lwhi+lwlo) + lb -> h (skip if LAST); bf16(hv) -> A_
// GEMM3: !LAST: hxbn = bf16(hv @ c1n) ; LAST: h1 = relu(hv @ lin1 + l1b)
// LDS: A 8K + B 32K + U 8K = 48 KB -> 3 blocks/CU; grid = N/32 = 626.
template<bool LAST>
__global__ __launch_bounds__(256, 3) void nodefused_kernel(
        const ushort* __restrict__ aggb,
        const ushort* __restrict__ c2hi, const ushort* __restrict__ c2lo,
        const float* __restrict__ c2b,
        const ushort* __restrict__ lwhi, const ushort* __restrict__ lwlo,
        const float* __restrict__ lb,
        const ushort* __restrict__ c1nhi, const ushort* __restrict__ c1nlo,
        const float* __restrict__ l1b,
        float* __restrict__ h, ushort* __restrict__ hxbn, float* __restrict__ h1,
        int mtiles) {
    __shared__ ushort A_[32 * 128];
    __shared__ ushort B_[128 * 128];
    __shared__ ushort U_[32 * 128];
    char* Ab = (char*)A_;
    char* Bb = (char*)B_;
    char* Ub = (char*)U_;
    const int tid  = threadIdx.x;
    const int lane = tid & 63;
    const int wave = tid >> 6;
    const int l15  = lane & 15;
    const int kgrp = (lane >> 4) * 8;
    const int wr = (wave & 1) * 16;       // row base within 32-row tile
    const int wc = (wave >> 1) * 4;       // cb base (4 cb = 64 cols)

    float b1c[4], b2c[4], b3c[4];
    #pragma unroll
    for (int cb = 0; cb < 4; ++cb) {
        int c = (wc + cb)*16 + l15;
        b1c[cb] = c2b[c];
        b2c[cb] = lb[c];
        b3c[cb] = LAST ? l1b[c] : 0.0f;
    }

    for (int mt = blockIdx.x; mt < mtiles; mt += gridDim.x) {
        __syncthreads();   // prior iter's A_/B_/U_ reads done
        // stage A = aggb tile (32 rows, bf16, swizzled): 2 passes
        #pragma unroll
        for (int p = 0; p < 2; ++p) {
            int rr = p * 16 + (tid >> 4);
            int k8 = (tid & 15) * 8;
            u16x8 v = *reinterpret_cast<const u16x8*>(&aggb[(size_t)(mt*32 + rr)*HD + k8]);
            *reinterpret_cast<u16x8*>(&Ab[rr*256 + ((2*k8) ^ ((rr & 7) << 4))]) = v;
        }

        f32x4 acc[4];
        // ---- GEMM1: acc = A @ (c2hi+c2lo) ----
        #pragma unroll
        for (int j = 0; j < 4; ++j) { acc[j].x=0.f; acc[j].y=0.f; acc[j].z=0.f; acc[j].w=0.f; }
        #pragma unroll
        for (int part = 0; part < 2; ++part) {
            const ushort* BT = part ? c2lo : c2hi;
            __syncthreads();
            #pragma unroll
            for (int p = 0; p < 8; ++p) {
                int rr = p * 16 + (tid >> 4);
                int k8 = (tid & 15) * 8;
                u16x8 v = *reinterpret_cast<const u16x8*>(&BT[(size_t)rr*128 + k8]);
                *reinterpret_cast<u16x8*>(&Bb[rr*256 + ((2*k8) ^ ((rr & 7) << 4))]) = v;
            }
            __syncthreads();
            #pragma unroll
            for (int ks = 0; ks < 4; ++ks) {
                int k = ks*32 + kgrp;
                int r = wr + l15;
                bf16x8 af = *reinterpret_cast<const bf16x8*>(&Ab[r*256 + ((2*k) ^ ((r & 7) << 4))]);
                #pragma unroll
                for (int cb = 0; cb < 4; ++cb) {
                    int c = (wc + cb)*16 + l15;
                    bf16x8 bv = *reinterpret_cast<const bf16x8*>(&Bb[c*256 + ((2*k) ^ ((c & 7) << 4))]);
                    acc[cb] = __builtin_amdgcn_mfma_f32_16x16x32_bf16(af, bv, acc[cb], 0, 0, 0);
                }
            }
        }
        // epilogue1: ssp -> U_
        #pragma unroll
        for (int cb = 0; cb < 4; ++cb) {
            int c = (wc + cb)*16 + l15;
            #pragma unroll
            for (int i = 0; i < 4; ++i) {
                int rrow = wr + (lane >> 4)*4 + i;
                ushort us = f2bf(ssp_f(acc[cb][i] + b1c[cb]));
                *reinterpret_cast<ushort*>(&Ub[rrow*256 + ((2*c) ^ ((rrow & 7) << 4))]) = us;
            }
        }

        // ---- GEMM2: acc = U @ (lwhi+lwlo) ----
        #pragma unroll
        for (int j = 0; j < 4; ++j) { acc[j].x=0.f; acc[j].y=0.f; acc[j].z=0.f; acc[j].w=0.f; }
        #pragma unroll
        for (int part = 0; part < 2; ++part) {
            const ushort* BT = part ? lwlo : lwhi;
            __syncthreads();     // U_ visible + prior B reads done
            #pragma unroll
            for (int p = 0; p < 8; ++p) {
                int rr = p * 16 + (tid >> 4);
                int k8 = (tid & 15) * 8;
                u16x8 v = *reinterpret_cast<const u16x8*>(&BT[(size_t)rr*128 + k8]);
                *reinterpret_cast<u16x8*>(&Bb[rr*256 + ((2*k8) ^ ((rr & 7) << 4))]) = v;
            }
            __syncthreads();
            #pragma unroll
            for (int ks = 0; ks < 4; ++ks) {
                int k = ks*32 + kgrp;
                int r = wr + l15;
                bf16x8 af = *reinterpret_cast<const bf16x8*>(&Ub[r*256 + ((2*k) ^ ((r & 7) << 4))]);
                #pragma unroll
                for (int cb = 0; cb < 4; ++cb) {
                    int c = (wc + cb)*16 + l15;
                    bf16x8 bv = *reinterpret_cast<const bf16x8*>(&Bb[c*256 + ((2*k) ^ ((c & 7) << 4))]);
                    acc[cb] = __builtin_amdgcn_mfma_f32_16x16x32_bf16(af, bv, acc[cb], 0, 0, 0);
                }
            }
        }
        // epilogue2: hv = h + acc + lb -> h (if !LAST); bf16(hv) -> A_ (A reads long done)
        #pragma unroll
        for (int cb = 0; cb < 4; ++cb) {
            int c = (wc + cb)*16 + l15;
            #pragma unroll
            for (int i = 0; i < 4; ++i) {
                int rrow = wr + (lane >> 4)*4 + i;
                int row = mt*32 + rrow;
                size_t off = (size_t)row * HD + c;
                float hv = h[off] + acc[cb][i] + b2c[cb];
                if (!LAST) h[off] = hv;
                *reinterpret_cast<ushort*>(&Ab[rrow*256 + ((2*c) ^ ((rrow & 7) << 4))]) = f2bf(hv);
            }
        }

        // ---- GEMM3: acc = A_(new h) @ (c1nhi+c1nlo) ----
        #pragma unroll
        for (int j = 0; j < 4; ++j) { acc[j].x=0.f; acc[j].y=0.f; acc[j].z=0.f; acc[j].w=0.f; }
        #pragma unroll
        for (int part = 0; part < 2; ++part) {
            const ushort* BT = part ? c1nlo : c1nhi;
            __syncthreads();     // new A_ visible + prior B reads done
            #pragma unroll
            for (int p = 0; p < 8; ++p) {
                int rr = p * 16 + (tid >> 4);
                int k8 = (tid & 15) * 8;
                u16x8 v = *reinterpret_cast<const u16x8*>(&BT[(size_t)rr*128 + k8]);
                *reinterpret_cast<u16x8*>(&Bb[rr*256 + ((2*k8) ^ ((rr & 7) << 4))]) = v;
            }
            __syncthreads();
            #pragma unroll
            for (int ks = 0; ks < 4; ++ks) {
                int k = ks*32 + kgrp;
                int r = wr + l15;
                bf16x8 af = *reinterpret_cast<const bf16x8*>(&Ab[r*256 + ((2*k) ^ ((r & 7) << 4))]);
                #pragma unroll
                for (int cb = 0; cb < 4; ++cb) {
                    int c = (wc + cb)*16 + l15;
                    bf16x8 bv = *reinterpret_cast<const bf16x8*>(&Bb[c*256 + ((2*k) ^ ((c & 7) << 4))]);
                    acc[cb] = __builtin_amdgcn_mfma_f32_16x16x32_bf16(af, bv, acc[cb], 0, 0, 0);
                }
            }
        }
        // epilogue3
        #pragma unroll
        for (int cb = 0; cb < 4; ++cb) {
            int c = (wc + cb)*16 + l15;
            #pragma unroll
            for (int i = 0; i < 4; ++i) {
                int row = mt*32 + wr + (lane >> 4)*4 + i;
                size_t off = (size_t)row * HD + c;
                if (LAST) h1[off] = fmaxf(acc[cb][i] + b3c[cb], 0.0f);
                else      hxbn[off] = f2bf(acc[cb][i]);
            }
        }
    }
}

// ================= fused gather-lerp-segment-sum (4-slot unrolled) ============
__global__ __launch_bounds__(256) void gathersum_kernel(
        const uint* __restrict__ Tp, const uint2* __restrict__ meta,
        const int* __restrict__ rowp, const ushort* __restrict__ hxb,
        ushort* __restrict__ aggb, int N) {
    const int lane = threadIdx.x & 63;
    const int n = blockIdx.x * 4 + (threadIdx.x >> 6);
    if (n >= N) return;
    const int c0 = lane * 2;
    const int s0 = rowp[n], s1 = rowp[n + 1];
    float a0=0.f, a1=0.f, a2=0.f, a3=0.f, a4=0.f, a5=0.f, a6=0.f, a7=0.f;
    int s = s0;
    for (; s + 4 <= s1; s += 4) {
        uint2 m0 = meta[s], m1 = meta[s+1], m2 = meta[s+2], m3 = meta[s+3];
        uint2 t0 = *reinterpret_cast<const uint2*>(&Tp[(size_t)(m0.x >> 16) * HD + c0]);
        uint2 t1 = *reinterpret_cast<const uint2*>(&Tp[(size_t)(m1.x >> 16) * HD + c0]);
        uint2 t2 = *reinterpret_cast<const uint2*>(&Tp[(size_t)(m2.x >> 16) * HD + c0]);
        uint2 t3 = *reinterpret_cast<const uint2*>(&Tp[(size_t)(m3.x >> 16) * HD + c0]);
        uint  h0 = *reinterpret_cast<const uint*>(&hxb[(size_t)(m0.x & 0xFFFFu) * HD + c0]);
        uint  h1 = *reinterpret_cast<const uint*>(&hxb[(size_t)(m1.x & 0xFFFFu) * HD + c0]);
        uint  h2 = *reinterpret_cast<const uint*>(&hxb[(size_t)(m2.x & 0xFFFFu) * HD + c0]);
        uint  h3 = *reinterpret_cast<const uint*>(&hxb[(size_t)(m3.x & 0xFFFFu) * HD + c0]);
        float wa, wb, glo, ghi;
        wa = bf2f((ushort)(m0.y & 0xFFFFu)); wb = bf2f((ushort)(m0.y >> 16));
        glo = wa*__uint_as_float(t0.x << 16) + wb*__uint_as_float(t0.x & 0xFFFF0000u);
        ghi = wa*__uint_as_float(t0.y << 16) + wb*__uint_as_float(t0.y & 0xFFFF0000u);
        a0 += glo * __uint_as_float(h0 << 16);
        a1 += ghi * __uint_as_float(h0 & 0xFFFF0000u);
        wa = bf2f((ushort)(m1.y & 0xFFFFu)); wb = bf2f((ushort)(m1.y >> 16));
        glo = wa*__uint_as_float(t1.x << 16) + wb*__uint_as_float(t1.x & 0xFFFF0000u);
        ghi = wa*__uint_as_float(t1.y << 16) + wb*__uint_as_float(t1.y & 0xFFFF0000u);
        a2 += glo * __uint_as_float(h1 << 16);
        a3 += ghi * __uint_as_float(h1 & 0xFFFF0000u);
        wa = bf2f((ushort)(m2.y & 0xFFFFu)); wb = bf2f((ushort)(m2.y >> 16));
        glo = wa*__uint_as_float(t2.x << 16) + wb*__uint_as_float(t2.x & 0xFFFF0000u);
        ghi = wa*__uint_as_float(t2.y << 16) + wb*__uint_as_float(t2.y & 0xFFFF0000u);
        a4 += glo * __uint_as_float(h2 << 16);
        a5 += ghi * __uint_as_float(h2 & 0xFFFF0000u);
        wa = bf2f((ushort)(m3.y & 0xFFFFu)); wb = bf2f((ushort)(m3.y >> 16));
        glo = wa*__uint_as_float(t3.x << 16) + wb*__uint_as_float(t3.x & 0xFFFF0000u);
        ghi = wa*__uint_as_float(t3.y << 16) + wb*__uint_as_float(t3.y & 0xFFFF0000u);
        a6 += glo * __uint_as_float(h3 << 16);
        a7 += ghi * __uint_as_float(h3 & 0xFFFF0000u);
    }
    for (; s < s1; ++s) {
        uint2 m0 = meta[s];
        uint2 t0 = *reinterpret_cast<const uint2*>(&Tp[(size_t)(m0.x >> 16) * HD + c0]);
        uint  h0 = *reinterpret_cast<const uint*>(&hxb[(size_t)(m0.x & 0xFFFFu) * HD + c0]);
        float wa = bf2f((ushort)(m0.y & 0xFFFFu)), wb = bf2f((ushort)(m0.y >> 16));
        float glo = wa*__uint_as_float(t0.x << 16) + wb*__uint_as_float(t0.x & 0xFFFF0000u);
        float ghi = wa*__uint_as_float(t0.y << 16) + wb*__uint_as_float(t0.y & 0xFFFF0000u);
        a0 += glo * __uint_as_float(h0 << 16);
        a1 += ghi * __uint_as_float(h0 & 0xFFFF0000u);
    }
    uint out = ((uint)f2bf(a0 + a2 + a4 + a6)) | (((uint)f2bf(a1 + a3 + a5 + a7)) << 16);
    *reinterpret_cast<uint*>(&aggb[(size_t)n * HD + c0]) = out;
}

// ================= mean pool =================
__global__ void pool_kernel(const float* __restrict__ h1, const int* __restrict__ batch,
                            float* __restrict__ gsum, float* __restrict__ gcnt, int N) {
    __shared__ float pool[NGRAPH][HD];
    __shared__ float cnt[NGRAPH];
    const int t = threadIdx.x;
    #pragma unroll
    for (int g = 0; g < NGRAPH; ++g) pool[g][t] = 0.0f;
    if (t < NGRAPH) cnt[t] = 0.0f;
    __syncthreads();
    int chunk = (N + gridDim.x - 1) / gridDim.x;
    int n0 = blockIdx.x * chunk, n1 = min(N, n0 + chunk);
    for (int n = n0; n < n1; ++n) {
        int b = batch[n];
        pool[b][t] += h1[(size_t)n * HD + t];
        if (t == 0) cnt[b] += 1.0f;
    }
    __syncthreads();
    #pragma unroll
    for (int g = 0; g < NGRAPH; ++g) atomicAdd(&gsum[g*HD + t], pool[g][t]);
    if (t < NGRAPH) atomicAdd(&gcnt[t], cnt[t]);
}

// ================= head =================
__global__ void finalize_kernel(const float* __restrict__ gsum, const float* __restrict__ gcnt,
                                const float* __restrict__ l1w, const float* __restrict__ l1b,
                                const float* __restrict__ l2w, const float* __restrict__ l2b,
                                float* __restrict__ d_out) {
    __shared__ float ge[HD];
    __shared__ float h2[HD];
    const int g = blockIdx.x, t = threadIdx.x;
    float cnt = fmaxf(gcnt[g], 1.0f);
    float v = gsum[g*HD + t] / cnt;
    d_out[g*HD + t] = v;
    ge[t] = v;
    __syncthreads();
    float acc = l1b[t];
    #pragma unroll 8
    for (int k = 0; k < HD; ++k) acc += ge[k] * l1w[k*HD + t];
    h2[t] = fmaxf(acc, 0.0f);
    __syncthreads();
    if (t < NCLS) {
        float o = l2b[t];
        #pragma unroll 8
        for (int k = 0; k < HD; ++k) o += h2[k] * l2w[k*NCLS + t];
        d_out[NGRAPH*HD + g*NCLS + t] = o;
    }
}

extern "C" void kernel_launch(void* const* d_in, const int* in_sizes, int n_in,
                              void* d_out, int out_size, void* d_ws, size_t ws_size,
                              hipStream_t stream) {
    const float* x     = (const float*)d_in[0];
    const float* pos   = (const float*)d_in[1];
    const int*   eidx  = (const int*)d_in[2];
    const int*   batch = (const int*)d_in[3];
    const float* emb_w = (const float*)d_in[4];
    const float* emb_b = (const float*)d_in[5];
    const float* m1w   = (const float*)d_in[6];
    const float* m1b   = (const float*)d_in[7];
    const float* m2w   = (const float*)d_in[8];
    const float* m2b   = (const float*)d_in[9];
    const float* c1w   = (const float*)d_in[10];
    const float* c2w   = (const float*)d_in[11];
    const float* c2b   = (const float*)d_in[12];
    const float* lw    = (const float*)d_in[13];
    const float* lb    = (const float*)d_in[14];
    const float* l1w   = (const float*)d_in[15];
    const float* l1b   = (const float*)d_in[16];
    const float* l2w   = (const float*)d_in[17];
    const float* l2b   = (const float*)d_in[18];

    const int N = in_sizes[0] / 21;          // 20000
    const int E = in_sizes[2] / 2;           // 640000
    const int* row = eidx;
    const int* col = eidx + E;
    const int NT64 = (N + 63) / 64;          // 313
    const int NT32 = (N + 31) / 32;          // 626
    const int NB   = (N + 255) / 256;        // 79
    const int Npad = NT64 * 64 + 64;

    size_t off = 0;
    char* base = (char*)d_ws;
    auto alloc = [&](size_t bytes) -> void* {
        off = (off + 255) & ~(size_t)255;
        void* p = base + off;
        off += bytes;
        return p;
    };
    int*    deg     = (int*)alloc((size_t)N * 4);
    int*    cursor  = (int*)alloc((size_t)N * 4);
    int*    rowp    = (int*)alloc((size_t)(N + 1) * 4);
    int*    bsum    = (int*)alloc(512 * 4);
    int*    boff    = (int*)alloc(512 * 4);
    uint2*  meta    = (uint2*)alloc((size_t)E * 8);
    float*  h       = (float*)alloc((size_t)Npad * HD * 4);
    ushort* hxb     = (ushort*)alloc((size_t)Npad * HD * 2);
    ushort* aggb    = (ushort*)alloc((size_t)Npad * HD * 2);
    float*  h1      = (float*)alloc((size_t)Npad * HD * 4);
    float*  T6      = (float*)alloc((size_t)6 * NTAB * HD * 4);
    uint*   P6      = (uint*)alloc((size_t)6 * NTAB * HD * 4);
    ushort* m1T     = (ushort*)alloc((size_t)6 * 128 * 64 * 2);
    ushort* nodeThi = (ushort*)alloc((size_t)19 * 128 * 128 * 2);
    ushort* nodeTlo = (ushort*)alloc((size_t)19 * 128 * 128 * 2);
    ushort* m2T     = (ushort*)alloc((size_t)6 * 128 * 128 * 2);
    float*  gsum    = (float*)alloc((size_t)NGRAPH * HD * 4);
    float*  gcnt    = (float*)alloc((size_t)NGRAPH * 4);

    // ---- one-time: weight prep + CSR + filter tables ----
    prep_kernel<<<1792, 256, 0, stream>>>(m1w, c1w, c2w, lw, l1w, m2w,
                                          m1T, nodeThi, nodeTlo, m2T);
    hipMemsetAsync(deg, 0, (size_t)N * 4, stream);
    hist_kernel<<<(E + 255)/256, 256, 0, stream>>>(col, deg, E);
    scan1_kernel<<<NB, 256, 0, stream>>>(deg, rowp, bsum, N);
    scan2_kernel<<<1, 256, 0, stream>>>(bsum, boff, NB, rowp + N);
    scan3_kernel<<<NB, 256, 0, stream>>>(rowp, boff, cursor, N);
    fill_kernel<<<(E + 255)/256, 256, 0, stream>>>(row, col, pos, cursor, meta, E);
    buildtab_kernel<<<6 * (NTAB/128), 256, 0, stream>>>(m1T, m2T, m1b, m2b, T6);
    packtab_kernel<<<(6*NTAB*HD + 255)/256, 256, 0, stream>>>(T6, P6);
    embed_kernel<<<(N*HD + 255)/256, 256, 0, stream>>>(x, emb_w, emb_b, h, N);

    // hxb for layer 0
    gemv64_kernel<<<NT64, 256, 0, stream>>>(h, nodeThi, nodeTlo, hxb, NT64);

    for (int l = 0; l < NLAYER; ++l) {
        const ushort* c2Thi = nodeThi + (size_t)(6 + l) * 16384;
        const ushort* c2Tlo = nodeTlo + (size_t)(6 + l) * 16384;
        const ushort* lThi  = nodeThi + (size_t)(12 + l) * 16384;
        const ushort* lTlo  = nodeTlo + (size_t)(12 + l) * 16384;

        gathersum_kernel<<<(N + 3)/4, 256, 0, stream>>>(
            P6 + (size_t)l * NTAB * HD, meta, rowp, hxb, aggb, N);

        if (l < NLAYER - 1) {
            const ushort* c1nhi = nodeThi + (size_t)(l + 1) * 16384;
            const ushort* c1nlo = nodeTlo + (size_t)(l + 1) * 16384;
            nodefused_kernel<false><<<NT32, 256, 0, stream>>>(
                aggb, c2Thi, c2Tlo, c2b + l*HD, lThi, lTlo, lb + l*HD,
                c1nhi, c1nlo, nullptr, h, hxb, nullptr, NT32);
        } else {
            const ushort* lin1hi = nodeThi + (size_t)18 * 16384;
            const ushort* lin1lo = nodeTlo + (size_t)18 * 16384;
            nodefused_kernel<true><<<NT32, 256, 0, stream>>>(
                aggb, c2Thi, c2Tlo, c2b + l*HD, lThi, lTlo, lb + l*HD,
                lin1hi, lin1lo, l1b, h, nullptr, h1, NT32);
        }
    }

    hipMemsetAsync(gsum, 0, (size_t)(NGRAPH*HD + NGRAPH) * 4, stream);
    pool_kernel<<<256, HD, 0, stream>>>(h1, batch, gsum, gcnt, N);
    finalize_kernel<<<NGRAPH, HD, 0, stream>>>(gsum, gcnt, l1w, l1b, l2w, l2b,
                                               (float*)d_out);
}

// Round 10
// 524.497 us; speedup vs baseline: 1.3798x; 1.3798x over previous
//
#include <hip/hip_runtime.h>
#include <hip/hip_bf16.h>

#define HD 128
#define NGAUSS 50
#define NLAYER 6
#define NGRAPH 16
#define NCLS 97
#define NTAB 2048
#define WMAX 12.0f

typedef __attribute__((ext_vector_type(8))) short bf16x8;
typedef __attribute__((ext_vector_type(4))) float f32x4;
typedef __attribute__((ext_vector_type(8))) ushort u16x8;
typedef __attribute__((ext_vector_type(4))) ushort u16x4;

__device__ __forceinline__ float ssp_f(float x) {
    float e = __expf(-fabsf(x));
    return fmaxf(x, 0.0f) + __logf(0.5f + 0.5f * e);
}
__device__ __forceinline__ ushort f2bf(float f) {   // RNE f32->bf16
    uint u = __float_as_uint(f);
    return (ushort)((u + 0x7FFFu + ((u >> 16) & 1u)) >> 16);
}
__device__ __forceinline__ float bf2f(ushort s) {
    return __uint_as_float(((uint)s) << 16);
}

// ================= CSR build =================
__global__ void hist_kernel(const int* __restrict__ col, int* __restrict__ deg, int E) {
    int e = blockIdx.x * blockDim.x + threadIdx.x;
    if (e < E) atomicAdd(&deg[col[e]], 1);
}

__global__ void scan1_kernel(const int* __restrict__ deg, int* __restrict__ rowp,
                             int* __restrict__ bsum, int N) {
    __shared__ int sm[256];
    const int t = threadIdx.x, i = blockIdx.x * 256 + t;
    int v = (i < N) ? deg[i] : 0;
    sm[t] = v;
    __syncthreads();
    for (int off = 1; off < 256; off <<= 1) {
        int x = sm[t];
        int a = (t >= off) ? sm[t - off] : 0;
        __syncthreads();
        sm[t] = x + a;
        __syncthreads();
    }
    if (i < N) rowp[i] = sm[t] - v;
    if (t == 255) bsum[blockIdx.x] = sm[255];
}
__global__ void scan2_kernel(const int* __restrict__ bsum, int* __restrict__ boff,
                             int NB, int* __restrict__ rowpN) {
    __shared__ int sm[256];
    const int t = threadIdx.x;
    int v = (t < NB) ? bsum[t] : 0;
    sm[t] = v;
    __syncthreads();
    for (int off = 1; off < 256; off <<= 1) {
        int x = sm[t];
        int a = (t >= off) ? sm[t - off] : 0;
        __syncthreads();
        sm[t] = x + a;
        __syncthreads();
    }
    if (t < NB) boff[t] = sm[t] - v;
    if (t == 255) *rowpN = sm[255];
}
__global__ void scan3_kernel(int* __restrict__ rowp, const int* __restrict__ boff,
                             int* __restrict__ cursor, int N) {
    int i = blockIdx.x * blockDim.x + threadIdx.x;
    if (i < N) {
        int r = rowp[i] + boff[i >> 8];
        rowp[i] = r;
        cursor[i] = r;
    }
}

// per-slot metadata (8 B): word0 = row | (tab_idx<<16); word1 = bf16{(1-f)*cenv} | bf16{f*cenv}<<16
__global__ void fill_kernel(const int* __restrict__ row, const int* __restrict__ col,
                            const float* __restrict__ pos, int* __restrict__ cursor,
                            uint2* __restrict__ meta, int E) {
    int e = blockIdx.x * blockDim.x + threadIdx.x;
    if (e >= E) return;
    int c = col[e], r = row[e];
    int slot = atomicAdd(&cursor[c], 1);
    float dx = pos[r*3+0] - pos[c*3+0];
    float dy = pos[r*3+1] - pos[c*3+1];
    float dz = pos[r*3+2] - pos[c*3+2];
    float w = sqrtf(dx*dx + dy*dy + dz*dz);
    float cenv = 0.5f * (cosf(w * 0.31415926535897931f) + 1.0f);
    const float invDW = (float)(NTAB - 1) / WMAX;
    float tt = w * invDW;
    int i = min((int)tt, NTAB - 1);
    float f = fminf(tt - (float)i, 1.0f);
    uint w0 = ((uint)r) | (((uint)i) << 16);
    uint w1 = ((uint)f2bf((1.0f - f) * cenv)) | (((uint)f2bf(f * cenv)) << 16);
    meta[slot] = make_uint2(w0, w1);
}

// ================= weight prep =================
__global__ void prep_kernel(const float* __restrict__ m1w, const float* __restrict__ c1w,
                            const float* __restrict__ c2w, const float* __restrict__ lw,
                            const float* __restrict__ l1w, const float* __restrict__ m2w,
                            ushort* __restrict__ m1T, ushort* __restrict__ nodeThi,
                            ushort* __restrict__ nodeTlo, ushort* __restrict__ m2T) {
    int idx = blockIdx.x * blockDim.x + threadIdx.x;
    const int S1 = 6*128*64, S2 = 19*128*128, S3 = 6*128*128;
    if (idx < S1) {
        int l = idx / 8192, r = idx % 8192, c = r / 64, k = r % 64;
        float v = (k < NGAUSS) ? m1w[(size_t)l*NGAUSS*128 + k*128 + c] : 0.0f;
        m1T[(size_t)l*8192 + c*64 + k] = f2bf(v);
    } else if (idx < S1 + S2) {
        int j = idx - S1;
        int m = j / 16384, r = j % 16384, c = r / 128, k = r % 128;
        const float* src;
        if (m < 6)       src = c1w + (size_t)m*16384;
        else if (m < 12) src = c2w + (size_t)(m-6)*16384;
        else if (m < 18) src = lw  + (size_t)(m-12)*16384;
        else             src = l1w;
        float v = src[k*128 + c];
        ushort hi = f2bf(v);
        nodeThi[(size_t)m*16384 + c*128 + k] = hi;
        nodeTlo[(size_t)m*16384 + c*128 + k] = f2bf(v - bf2f(hi));
    } else if (idx < S1 + S2 + S3) {
        int j = idx - S1 - S2;
        int l = j / 16384, r = j % 16384, c = r / 128, k = r % 128;
        m2T[(size_t)l*16384 + c*128 + k] = f2bf(m2w[(size_t)l*16384 + k*128 + c]);
    }
}

// ================= embedding =================
__global__ void embed_kernel(const float* __restrict__ x,
                             const float* __restrict__ emb_w, const float* __restrict__ emb_b,
                             float* __restrict__ h, int N) {
    int idx = blockIdx.x * blockDim.x + threadIdx.x;
    if (idx >= N * HD) return;
    int n = idx >> 7, t = idx & 127;
    float acc = emb_b[t];
    #pragma unroll
    for (int a = 0; a < 21; ++a) acc += x[n*21 + a] * emb_w[a*HD + t];
    h[idx] = acc;
}

// ================= filter table build (proven structure, 2048-pt grid) ======
__global__ __launch_bounds__(256, 2) void buildtab_kernel(
        const ushort* __restrict__ m1T_all, const ushort* __restrict__ m2T_all,
        const float* __restrict__ m1b_all, const float* __restrict__ m2b_all,
        float* __restrict__ T6) {
    __shared__ ushort A1[128 * 64];
    __shared__ ushort B1[128 * 64];
    __shared__ ushort U [128 * 128];
    char* A1b = (char*)A1;
    char* B1b = (char*)B1;
    char* Ub  = (char*)U;
    const int tid  = threadIdx.x;
    const int lane = tid & 63;
    const int wave = tid >> 6;
    const int l15  = lane & 15;
    const int kgrp = (lane >> 4) * 8;
    const int rbase = wave * 32;
    const int layer = blockIdx.x >> 4;
    const int mt    = blockIdx.x & 15;
    const ushort* m1T = m1T_all + (size_t)layer * 8192;
    const ushort* m2T = m2T_all + (size_t)layer * 16384;
    const float*  m1b = m1b_all + layer * HD;
    const float*  m2b = m2b_all + layer * HD;

    #pragma unroll
    for (int p = 0; p < 4; ++p) {
        int rr = p * 32 + (tid >> 3);
        int k8 = (tid & 7) * 8;
        u16x8 v = *reinterpret_cast<const u16x8*>(&m1T[(size_t)rr * 64 + k8]);
        *reinterpret_cast<u16x8*>(&B1b[rr*128 + ((2*k8) ^ ((rr & 7) << 4))]) = v;
    }

    float b1c[8], b2c[8];
    #pragma unroll
    for (int cb = 0; cb < 8; ++cb) { b1c[cb] = m1b[cb*16 + l15]; b2c[cb] = m2b[cb*16 + l15]; }

    const float step = 10.0f / 49.0f;
    const float coeff = -0.5f / (step * step);
    const float DW = WMAX / (float)(NTAB - 1);

    #pragma unroll
    for (int p = 0; p < 4; ++p) {
        int rr = p * 32 + (tid >> 3);
        int k8 = (tid & 7) * 8;
        float w = (float)(mt*128 + rr) * DW;
        u16x8 v;
        #pragma unroll
        for (int j = 0; j < 8; ++j) {
            int k = k8 + j;
            float d = w - (float)k * step;
            float g = (k < NGAUSS) ? __expf(coeff * d * d) : 0.0f;
            v[j] = f2bf(g);
        }
        *reinterpret_cast<u16x8*>(&A1b[rr*128 + ((2*k8) ^ ((rr & 7) << 4))]) = v;
    }
    __syncthreads();

    f32x4 acc1[2][8];
    #pragma unroll
    for (int i = 0; i < 2; ++i)
        #pragma unroll
        for (int j = 0; j < 8; ++j) { acc1[i][j].x=0.f; acc1[i][j].y=0.f; acc1[i][j].z=0.f; acc1[i][j].w=0.f; }
    #pragma unroll
    for (int ks = 0; ks < 2; ++ks) {
        int k = ks*32 + kgrp;
        bf16x8 af[2];
        #pragma unroll
        for (int rt = 0; rt < 2; ++rt) {
            int r = rbase + rt*16 + l15;
            af[rt] = *reinterpret_cast<const bf16x8*>(&A1b[r*128 + ((2*k) ^ ((r & 7) << 4))]);
        }
        #pragma unroll
        for (int cb = 0; cb < 8; ++cb) {
            int c = cb*16 + l15;
            bf16x8 bv = *reinterpret_cast<const bf16x8*>(&B1b[c*128 + ((2*k) ^ ((c & 7) << 4))]);
            acc1[0][cb] = __builtin_amdgcn_mfma_f32_16x16x32_bf16(af[0], bv, acc1[0][cb], 0, 0, 0);
            acc1[1][cb] = __builtin_amdgcn_mfma_f32_16x16x32_bf16(af[1], bv, acc1[1][cb], 0, 0, 0);
        }
    }
    #pragma unroll
    for (int rt = 0; rt < 2; ++rt) {
        #pragma unroll
        for (int cb = 0; cb < 8; ++cb) {
            int c = cb*16 + l15;
            #pragma unroll
            for (int i = 0; i < 4; ++i) {
                int rrow = rbase + rt*16 + (lane >> 4)*4 + i;
                ushort us = f2bf(ssp_f(acc1[rt][cb][i] + b1c[cb]));
                *reinterpret_cast<ushort*>(&Ub[rrow*256 + ((2*c) ^ ((rrow & 7) << 4))]) = us;
            }
        }
    }
    __syncthreads();

    f32x4 acc2[2][8];
    #pragma unroll
    for (int i = 0; i < 2; ++i)
        #pragma unroll
        for (int j = 0; j < 8; ++j) { acc2[i][j].x=0.f; acc2[i][j].y=0.f; acc2[i][j].z=0.f; acc2[i][j].w=0.f; }
    #pragma unroll
    for (int kh = 0; kh < 2; ++kh) {
        if (kh) __syncthreads();
        #pragma unroll
        for (int p = 0; p < 4; ++p) {
            int rr = p * 32 + (tid >> 3);
            int kk = (tid & 7) * 8;
            u16x8 v = *reinterpret_cast<const u16x8*>(&m2T[(size_t)rr*128 + kh*64 + kk]);
            *reinterpret_cast<u16x8*>(&A1b[rr*128 + ((2*kk) ^ ((rr & 7) << 4))]) = v;
        }
        __syncthreads();
        #pragma unroll
        for (int ks2 = 0; ks2 < 2; ++ks2) {
            int ku = kh*64 + ks2*32 + kgrp;
            int kb = ks2*32 + kgrp;
            bf16x8 af[2];
            #pragma unroll
            for (int rt = 0; rt < 2; ++rt) {
                int r = rbase + rt*16 + l15;
                af[rt] = *reinterpret_cast<const bf16x8*>(&Ub[r*256 + ((2*ku) ^ ((r & 7) << 4))]);
            }
            #pragma unroll
            for (int cb = 0; cb < 8; ++cb) {
                int c = cb*16 + l15;
                bf16x8 bv = *reinterpret_cast<const bf16x8*>(&A1b[c*128 + ((2*kb) ^ ((c & 7) << 4))]);
                acc2[0][cb] = __builtin_amdgcn_mfma_f32_16x16x32_bf16(af[0], bv, acc2[0][cb], 0, 0, 0);
                acc2[1][cb] = __builtin_amdgcn_mfma_f32_16x16x32_bf16(af[1], bv, acc2[1][cb], 0, 0, 0);
            }
        }
    }

    #pragma unroll
    for (int rt = 0; rt < 2; ++rt) {
        #pragma unroll
        for (int cb = 0; cb < 8; ++cb) {
            int c = cb*16 + l15;
            #pragma unroll
            for (int i = 0; i < 4; ++i) {
                int rrow = rbase + rt*16 + (lane >> 4)*4 + i;
                T6[((size_t)layer*NTAB + mt*128 + rrow) * HD + c] = acc2[rt][cb][i] + b2c[cb];
            }
        }
    }
}

// pack table rows i,i+1 as {bf16,bf16} in one u32
__global__ void packtab_kernel(const float* __restrict__ T6, uint* __restrict__ P6) {
    int idx = blockIdx.x * blockDim.x + threadIdx.x;
    if (idx >= 6 * NTAB * HD) return;
    int r = (idx >> 7) & (NTAB - 1);
    float v0 = T6[idx];
    float v1 = (r + 1 < NTAB) ? T6[idx + HD] : v0;
    P6[idx] = ((uint)f2bf(v0)) | (((uint)f2bf(v1)) << 16);
}

// ============ persistent-weight 64-row GEMV: out = EPI(h @ (Bhi+Blo)) ============
// B' resident in LDS as K-doubled split [128c][256k] (hi | lo) = 64KB; A 16KB -> 80KB.
// EPI 4: bias + relu -> f32 ; EPI 5: -> bf16.  2 syncs per tile.
template<int EPI>
__global__ __launch_bounds__(256) void gemv64_kernel(
        const float* __restrict__ A, const ushort* __restrict__ BThi,
        const ushort* __restrict__ BTlo, const float* __restrict__ bias,
        float* __restrict__ fdst, ushort* __restrict__ bdst, int mtiles) {
    __shared__ ushort Bw[128 * 256];   // 64KB
    __shared__ ushort A_[64 * 128];    // 16KB
    char* Bwb = (char*)Bw;
    char* Ab  = (char*)A_;
    const int tid  = threadIdx.x;
    const int lane = tid & 63;
    const int wave = tid >> 6;
    const int l15  = lane & 15;
    const int kgrp = (lane >> 4) * 8;
    const int rbase = wave * 16;

    // stage B' once (16 passes)
    #pragma unroll
    for (int p = 0; p < 16; ++p) {
        int idx = p * 256 + tid;
        int c = idx >> 5;
        int k8 = (idx & 31) * 8;
        const ushort* src = (k8 < 128) ? BThi : BTlo;
        u16x8 v = *reinterpret_cast<const u16x8*>(&src[(size_t)c*128 + (k8 & 127)]);
        *reinterpret_cast<u16x8*>(&Bwb[c*512 + ((2*k8) ^ ((c & 7) << 4))]) = v;
    }
    float bt[8];
    if (EPI == 4) {
        #pragma unroll
        for (int cb = 0; cb < 8; ++cb) bt[cb] = bias[cb*16 + l15];
    }
    __syncthreads();

    for (int mt = blockIdx.x; mt < mtiles; mt += gridDim.x) {
        // stage A (f32 -> bf16, swizzled)
        #pragma unroll
        for (int p = 0; p < 8; ++p) {
            int rr = p * 8 + (tid >> 5);
            int k4 = (tid & 31) * 4;
            f32x4 v = *reinterpret_cast<const f32x4*>(&A[(size_t)(mt*64 + rr)*HD + k4]);
            u16x4 b;
            b.x = f2bf(v.x); b.y = f2bf(v.y); b.z = f2bf(v.z); b.w = f2bf(v.w);
            *reinterpret_cast<u16x4*>(&Ab[rr*256 + ((2*k4) ^ ((rr & 7) << 4))]) = b;
        }
        __syncthreads();

        bf16x8 af[4];
        {
            int r = rbase + l15;
            #pragma unroll
            for (int q = 0; q < 4; ++q)
                af[q] = *reinterpret_cast<const bf16x8*>(&Ab[r*256 + ((2*(q*32 + kgrp)) ^ ((r & 7) << 4))]);
        }
        f32x4 acc[8];
        #pragma unroll
        for (int j = 0; j < 8; ++j) { acc[j].x=0.f; acc[j].y=0.f; acc[j].z=0.f; acc[j].w=0.f; }
        #pragma unroll
        for (int ks = 0; ks < 8; ++ks) {
            int kB = ks*32 + kgrp;
            #pragma unroll
            for (int cb = 0; cb < 8; ++cb) {
                int c = cb*16 + l15;
                bf16x8 bv = *reinterpret_cast<const bf16x8*>(&Bwb[c*512 + ((2*kB) ^ ((c & 7) << 4))]);
                acc[cb] = __builtin_amdgcn_mfma_f32_16x16x32_bf16(af[ks & 3], bv, acc[cb], 0, 0, 0);
            }
        }

        #pragma unroll
        for (int cb = 0; cb < 8; ++cb) {
            int c = cb*16 + l15;
            #pragma unroll
            for (int i = 0; i < 4; ++i) {
                int row = mt*64 + rbase + (lane >> 4)*4 + i;
                size_t off = (size_t)row * HD + c;
                if (EPI == 4) fdst[off] = fmaxf(acc[cb][i] + bt[cb], 0.0f);
                else          bdst[off] = f2bf(acc[cb][i]);
            }
        }
        __syncthreads();   // A_ reads done before next tile's stage
    }
}

// ======== persistent-weight fused node block (32-row tiles, 512 threads) ========
// h += ssp(aggb @ (c2hi+c2lo) + c2b) @ (lwhi+lwlo) + lb
// LDS: W1' 64K (c2 split K=256) + W2' 64K (lw split) + BUF 8K (A then U) = 136KB.
// Waves: 8 = 2 row-halves(16) x 4 col-quarters(2 cb = 32 cols). 4 syncs/tile.
__global__ __launch_bounds__(512, 1) void nodefused_kernel(
        const ushort* __restrict__ aggb,
        const ushort* __restrict__ c2hi, const ushort* __restrict__ c2lo,
        const float* __restrict__ c2b,
        const ushort* __restrict__ lwhi, const ushort* __restrict__ lwlo,
        const float* __restrict__ lb,
        float* __restrict__ h, int mtiles) {
    __shared__ ushort W1[128 * 256];   // 64KB
    __shared__ ushort W2[128 * 256];   // 64KB
    __shared__ ushort BUF[32 * 128];   // 8KB (A, then U)
    char* W1b = (char*)W1;
    char* W2b = (char*)W2;
    char* Bu  = (char*)BUF;
    const int tid  = threadIdx.x;
    const int lane = tid & 63;
    const int wave = tid >> 6;
    const int l15  = lane & 15;
    const int kgrp = (lane >> 4) * 8;
    const int wr = (wave & 1) * 16;     // row base (16 rows per wave)
    const int wc = (wave >> 1) * 2;     // cb base (2 cb = 32 cols per wave)

    // stage W1', W2' once (8 passes each)
    #pragma unroll
    for (int p = 0; p < 8; ++p) {
        int idx = p * 512 + tid;
        int c = idx >> 5;
        int k8 = (idx & 31) * 8;
        const ushort* s1 = (k8 < 128) ? c2hi : c2lo;
        u16x8 v1 = *reinterpret_cast<const u16x8*>(&s1[(size_t)c*128 + (k8 & 127)]);
        *reinterpret_cast<u16x8*>(&W1b[c*512 + ((2*k8) ^ ((c & 7) << 4))]) = v1;
        const ushort* s2 = (k8 < 128) ? lwhi : lwlo;
        u16x8 v2 = *reinterpret_cast<const u16x8*>(&s2[(size_t)c*128 + (k8 & 127)]);
        *reinterpret_cast<u16x8*>(&W2b[c*512 + ((2*k8) ^ ((c & 7) << 4))]) = v2;
    }
    float b1c[2], b2c[2];
    #pragma unroll
    for (int cb = 0; cb < 2; ++cb) {
        int c = (wc + cb)*16 + l15;
        b1c[cb] = c2b[c];
        b2c[cb] = lb[c];
    }
    __syncthreads();

    for (int mt = blockIdx.x; mt < mtiles; mt += gridDim.x) {
        // stage A = aggb tile (1 pass of 512 u16x8)
        {
            int rr = tid >> 4;
            int k8 = (tid & 15) * 8;
            u16x8 v = *reinterpret_cast<const u16x8*>(&aggb[(size_t)(mt*32 + rr)*HD + k8]);
            *reinterpret_cast<u16x8*>(&Bu[rr*256 + ((2*k8) ^ ((rr & 7) << 4))]) = v;
        }
        // prefetch h (needed at epilogue2; latency hides under both GEMMs)
        float hp[2][4];
        #pragma unroll
        for (int cb = 0; cb < 2; ++cb) {
            int c = (wc + cb)*16 + l15;
            #pragma unroll
            for (int i = 0; i < 4; ++i) {
                int row = mt*32 + wr + (lane >> 4)*4 + i;
                hp[cb][i] = h[(size_t)row * HD + c];
            }
        }
        __syncthreads();

        // ---- GEMM1: acc = A @ c2' (K=256 split) ----
        bf16x8 af[4];
        {
            int r = wr + l15;
            #pragma unroll
            for (int q = 0; q < 4; ++q)
                af[q] = *reinterpret_cast<const bf16x8*>(&Bu[r*256 + ((2*(q*32 + kgrp)) ^ ((r & 7) << 4))]);
        }
        f32x4 acc[2];
        #pragma unroll
        for (int j = 0; j < 2; ++j) { acc[j].x=0.f; acc[j].y=0.f; acc[j].z=0.f; acc[j].w=0.f; }
        #pragma unroll
        for (int ks = 0; ks < 8; ++ks) {
            int kB = ks*32 + kgrp;
            #pragma unroll
            for (int cb = 0; cb < 2; ++cb) {
                int c = (wc + cb)*16 + l15;
                bf16x8 bv = *reinterpret_cast<const bf16x8*>(&W1b[c*512 + ((2*kB) ^ ((c & 7) << 4))]);
                acc[cb] = __builtin_amdgcn_mfma_f32_16x16x32_bf16(af[ks & 3], bv, acc[cb], 0, 0, 0);
            }
        }
        __syncthreads();   // all A reads done -> BUF reusable

        // epilogue1: ssp -> BUF (U role)
        #pragma unroll
        for (int cb = 0; cb < 2; ++cb) {
            int c = (wc + cb)*16 + l15;
            #pragma unroll
            for (int i = 0; i < 4; ++i) {
                int rrow = wr + (lane >> 4)*4 + i;
                ushort us = f2bf(ssp_f(acc[cb][i] + b1c[cb]));
                *reinterpret_cast<ushort*>(&Bu[rrow*256 + ((2*c) ^ ((rrow & 7) << 4))]) = us;
            }
        }
        __syncthreads();   // U visible

        // ---- GEMM2: acc = U @ lw' (K=256 split) ----
        {
            int r = wr + l15;
            #pragma unroll
            for (int q = 0; q < 4; ++q)
                af[q] = *reinterpret_cast<const bf16x8*>(&Bu[r*256 + ((2*(q*32 + kgrp)) ^ ((r & 7) << 4))]);
        }
        #pragma unroll
        for (int j = 0; j < 2; ++j) { acc[j].x=0.f; acc[j].y=0.f; acc[j].z=0.f; acc[j].w=0.f; }
        #pragma unroll
        for (int ks = 0; ks < 8; ++ks) {
            int kB = ks*32 + kgrp;
            #pragma unroll
            for (int cb = 0; cb < 2; ++cb) {
                int c = (wc + cb)*16 + l15;
                bf16x8 bv = *reinterpret_cast<const bf16x8*>(&W2b[c*512 + ((2*kB) ^ ((c & 7) << 4))]);
                acc[cb] = __builtin_amdgcn_mfma_f32_16x16x32_bf16(af[ks & 3], bv, acc[cb], 0, 0, 0);
            }
        }
        // epilogue2: h = h + acc + lb
        #pragma unroll
        for (int cb = 0; cb < 2; ++cb) {
            int c = (wc + cb)*16 + l15;
            #pragma unroll
            for (int i = 0; i < 4; ++i) {
                int row = mt*32 + wr + (lane >> 4)*4 + i;
                h[(size_t)row * HD + c] = hp[cb][i] + acc[cb][i] + b2c[cb];
            }
        }
        __syncthreads();   // U reads done before next tile's A stage
    }
}

// ================= fused gather-lerp-segment-sum (4-slot unrolled) ============
__global__ __launch_bounds__(256) void gathersum_kernel(
        const uint* __restrict__ Tp, const uint2* __restrict__ meta,
        const int* __restrict__ rowp, const ushort* __restrict__ hxb,
        ushort* __restrict__ aggb, int N) {
    const int lane = threadIdx.x & 63;
    const int n = blockIdx.x * 4 + (threadIdx.x >> 6);
    if (n >= N) return;
    const int c0 = lane * 2;
    const int s0 = rowp[n], s1 = rowp[n + 1];
    float a0=0.f, a1=0.f, a2=0.f, a3=0.f, a4=0.f, a5=0.f, a6=0.f, a7=0.f;
    int s = s0;
    for (; s + 4 <= s1; s += 4) {
        uint2 m0 = meta[s], m1 = meta[s+1], m2 = meta[s+2], m3 = meta[s+3];
        uint2 t0 = *reinterpret_cast<const uint2*>(&Tp[(size_t)(m0.x >> 16) * HD + c0]);
        uint2 t1 = *reinterpret_cast<const uint2*>(&Tp[(size_t)(m1.x >> 16) * HD + c0]);
        uint2 t2 = *reinterpret_cast<const uint2*>(&Tp[(size_t)(m2.x >> 16) * HD + c0]);
        uint2 t3 = *reinterpret_cast<const uint2*>(&Tp[(size_t)(m3.x >> 16) * HD + c0]);
        uint  h0 = *reinterpret_cast<const uint*>(&hxb[(size_t)(m0.x & 0xFFFFu) * HD + c0]);
        uint  h1 = *reinterpret_cast<const uint*>(&hxb[(size_t)(m1.x & 0xFFFFu) * HD + c0]);
        uint  h2 = *reinterpret_cast<const uint*>(&hxb[(size_t)(m2.x & 0xFFFFu) * HD + c0]);
        uint  h3 = *reinterpret_cast<const uint*>(&hxb[(size_t)(m3.x & 0xFFFFu) * HD + c0]);
        float wa, wb, glo, ghi;
        wa = bf2f((ushort)(m0.y & 0xFFFFu)); wb = bf2f((ushort)(m0.y >> 16));
        glo = wa*__uint_as_float(t0.x << 16) + wb*__uint_as_float(t0.x & 0xFFFF0000u);
        ghi = wa*__uint_as_float(t0.y << 16) + wb*__uint_as_float(t0.y & 0xFFFF0000u);
        a0 += glo * __uint_as_float(h0 << 16);
        a1 += ghi * __uint_as_float(h0 & 0xFFFF0000u);
        wa = bf2f((ushort)(m1.y & 0xFFFFu)); wb = bf2f((ushort)(m1.y >> 16));
        glo = wa*__uint_as_float(t1.x << 16) + wb*__uint_as_float(t1.x & 0xFFFF0000u);
        ghi = wa*__uint_as_float(t1.y << 16) + wb*__uint_as_float(t1.y & 0xFFFF0000u);
        a2 += glo * __uint_as_float(h1 << 16);
        a3 += ghi * __uint_as_float(h1 & 0xFFFF0000u);
        wa = bf2f((ushort)(m2.y & 0xFFFFu)); wb = bf2f((ushort)(m2.y >> 16));
        glo = wa*__uint_as_float(t2.x << 16) + wb*__uint_as_float(t2.x & 0xFFFF0000u);
        ghi = wa*__uint_as_float(t2.y << 16) + wb*__uint_as_float(t2.y & 0xFFFF0000u);
        a4 += glo * __uint_as_float(h2 << 16);
        a5 += ghi * __uint_as_float(h2 & 0xFFFF0000u);
        wa = bf2f((ushort)(m3.y & 0xFFFFu)); wb = bf2f((ushort)(m3.y >> 16));
        glo = wa*__uint_as_float(t3.x << 16) + wb*__uint_as_float(t3.x & 0xFFFF0000u);
        ghi = wa*__uint_as_float(t3.y << 16) + wb*__uint_as_float(t3.y & 0xFFFF0000u);
        a6 += glo * __uint_as_float(h3 << 16);
        a7 += ghi * __uint_as_float(h3 & 0xFFFF0000u);
    }
    for (; s < s1; ++s) {
        uint2 m0 = meta[s];
        uint2 t0 = *reinterpret_cast<const uint2*>(&Tp[(size_t)(m0.x >> 16) * HD + c0]);
        uint  h0 = *reinterpret_cast<const uint*>(&hxb[(size_t)(m0.x & 0xFFFFu) * HD + c0]);
        float wa = bf2f((ushort)(m0.y & 0xFFFFu)), wb = bf2f((ushort)(m0.y >> 16));
        float glo = wa*__uint_as_float(t0.x << 16) + wb*__uint_as_float(t0.x & 0xFFFF0000u);
        float ghi = wa*__uint_as_float(t0.y << 16) + wb*__uint_as_float(t0.y & 0xFFFF0000u);
        a0 += glo * __uint_as_float(h0 << 16);
        a1 += ghi * __uint_as_float(h0 & 0xFFFF0000u);
    }
    uint out = ((uint)f2bf(a0 + a2 + a4 + a6)) | (((uint)f2bf(a1 + a3 + a5 + a7)) << 16);
    *reinterpret_cast<uint*>(&aggb[(size_t)n * HD + c0]) = out;
}

// ================= mean pool =================
__global__ void pool_kernel(const float* __restrict__ h1, const int* __restrict__ batch,
                            float* __restrict__ gsum, float* __restrict__ gcnt, int N) {
    __shared__ float pool[NGRAPH][HD];
    __shared__ float cnt[NGRAPH];
    const int t = threadIdx.x;
    #pragma unroll
    for (int g = 0; g < NGRAPH; ++g) pool[g][t] = 0.0f;
    if (t < NGRAPH) cnt[t] = 0.0f;
    __syncthreads();
    int chunk = (N + gridDim.x - 1) / gridDim.x;
    int n0 = blockIdx.x * chunk, n1 = min(N, n0 + chunk);
    for (int n = n0; n < n1; ++n) {
        int b = batch[n];
        pool[b][t] += h1[(size_t)n * HD + t];
        if (t == 0) cnt[b] += 1.0f;
    }
    __syncthreads();
    #pragma unroll
    for (int g = 0; g < NGRAPH; ++g) atomicAdd(&gsum[g*HD + t], pool[g][t]);
    if (t < NGRAPH) atomicAdd(&gcnt[t], cnt[t]);
}

// ================= head =================
__global__ void finalize_kernel(const float* __restrict__ gsum, const float* __restrict__ gcnt,
                                const float* __restrict__ l1w, const float* __restrict__ l1b,
                                const float* __restrict__ l2w, const float* __restrict__ l2b,
                                float* __restrict__ d_out) {
    __shared__ float ge[HD];
    __shared__ float h2[HD];
    const int g = blockIdx.x, t = threadIdx.x;
    float cnt = fmaxf(gcnt[g], 1.0f);
    float v = gsum[g*HD + t] / cnt;
    d_out[g*HD + t] = v;
    ge[t] = v;
    __syncthreads();
    float acc = l1b[t];
    #pragma unroll 8
    for (int k = 0; k < HD; ++k) acc += ge[k] * l1w[k*HD + t];
    h2[t] = fmaxf(acc, 0.0f);
    __syncthreads();
    if (t < NCLS) {
        float o = l2b[t];
        #pragma unroll 8
        for (int k = 0; k < HD; ++k) o += h2[k] * l2w[k*NCLS + t];
        d_out[NGRAPH*HD + g*NCLS + t] = o;
    }
}

extern "C" void kernel_launch(void* const* d_in, const int* in_sizes, int n_in,
                              void* d_out, int out_size, void* d_ws, size_t ws_size,
                              hipStream_t stream) {
    const float* x     = (const float*)d_in[0];
    const float* pos   = (const float*)d_in[1];
    const int*   eidx  = (const int*)d_in[2];
    const int*   batch = (const int*)d_in[3];
    const float* emb_w = (const float*)d_in[4];
    const float* emb_b = (const float*)d_in[5];
    const float* m1w   = (const float*)d_in[6];
    const float* m1b   = (const float*)d_in[7];
    const float* m2w   = (const float*)d_in[8];
    const float* m2b   = (const float*)d_in[9];
    const float* c1w   = (const float*)d_in[10];
    const float* c2w   = (const float*)d_in[11];
    const float* c2b   = (const float*)d_in[12];
    const float* lw    = (const float*)d_in[13];
    const float* lb    = (const float*)d_in[14];
    const float* l1w   = (const float*)d_in[15];
    const float* l1b   = (const float*)d_in[16];
    const float* l2w   = (const float*)d_in[17];
    const float* l2b   = (const float*)d_in[18];

    const int N = in_sizes[0] / 21;          // 20000
    const int E = in_sizes[2] / 2;           // 640000
    const int* row = eidx;
    const int* col = eidx + E;
    const int NT64 = (N + 63) / 64;          // 313
    const int NT32 = (N + 31) / 32;          // 625
    const int NB   = (N + 255) / 256;        // 79
    const int Npad = NT64 * 64 + 64;

    size_t off = 0;
    char* base = (char*)d_ws;
    auto alloc = [&](size_t bytes) -> void* {
        off = (off + 255) & ~(size_t)255;
        void* p = base + off;
        off += bytes;
        return p;
    };
    int*    deg     = (int*)alloc((size_t)N * 4);
    int*    cursor  = (int*)alloc((size_t)N * 4);
    int*    rowp    = (int*)alloc((size_t)(N + 1) * 4);
    int*    bsum    = (int*)alloc(512 * 4);
    int*    boff    = (int*)alloc(512 * 4);
    uint2*  meta    = (uint2*)alloc((size_t)E * 8);
    float*  h       = (float*)alloc((size_t)Npad * HD * 4);
    ushort* hxb     = (ushort*)alloc((size_t)Npad * HD * 2);
    ushort* aggb    = (ushort*)alloc((size_t)Npad * HD * 2);
    float*  h1      = (float*)alloc((size_t)Npad * HD * 4);
    float*  T6      = (float*)alloc((size_t)6 * NTAB * HD * 4);
    uint*   P6      = (uint*)alloc((size_t)6 * NTAB * HD * 4);
    ushort* m1T     = (ushort*)alloc((size_t)6 * 128 * 64 * 2);
    ushort* nodeThi = (ushort*)alloc((size_t)19 * 128 * 128 * 2);
    ushort* nodeTlo = (ushort*)alloc((size_t)19 * 128 * 128 * 2);
    ushort* m2T     = (ushort*)alloc((size_t)6 * 128 * 128 * 2);
    float*  gsum    = (float*)alloc((size_t)NGRAPH * HD * 4);
    float*  gcnt    = (float*)alloc((size_t)NGRAPH * 4);

    // ---- one-time: weight prep + CSR + filter tables ----
    prep_kernel<<<1792, 256, 0, stream>>>(m1w, c1w, c2w, lw, l1w, m2w,
                                          m1T, nodeThi, nodeTlo, m2T);
    hipMemsetAsync(deg, 0, (size_t)N * 4, stream);
    hist_kernel<<<(E + 255)/256, 256, 0, stream>>>(col, deg, E);
    scan1_kernel<<<NB, 256, 0, stream>>>(deg, rowp, bsum, N);
    scan2_kernel<<<1, 256, 0, stream>>>(bsum, boff, NB, rowp + N);
    scan3_kernel<<<NB, 256, 0, stream>>>(rowp, boff, cursor, N);
    fill_kernel<<<(E + 255)/256, 256, 0, stream>>>(row, col, pos, cursor, meta, E);
    buildtab_kernel<<<6 * (NTAB/128), 256, 0, stream>>>(m1T, m2T, m1b, m2b, T6);
    packtab_kernel<<<(6*NTAB*HD + 255)/256, 256, 0, stream>>>(T6, P6);
    embed_kernel<<<(N*HD + 255)/256, 256, 0, stream>>>(x, emb_w, emb_b, h, N);

    // hxb for layer 0
    gemv64_kernel<5><<<NT64, 256, 0, stream>>>(h, nodeThi, nodeTlo, nullptr,
                                               nullptr, hxb, NT64);

    for (int l = 0; l < NLAYER; ++l) {
        const ushort* c2Thi = nodeThi + (size_t)(6 + l) * 16384;
        const ushort* c2Tlo = nodeTlo + (size_t)(6 + l) * 16384;
        const ushort* lThi  = nodeThi + (size_t)(12 + l) * 16384;
        const ushort* lTlo  = nodeTlo + (size_t)(12 + l) * 16384;

        gathersum_kernel<<<(N + 3)/4, 256, 0, stream>>>(
            P6 + (size_t)l * NTAB * HD, meta, rowp, hxb, aggb, N);

        nodefused_kernel<<<256, 512, 0, stream>>>(
            aggb, c2Thi, c2Tlo, c2b + l*HD, lThi, lTlo, lb + l*HD, h, NT32);

        if (l < NLAYER - 1) {
            gemv64_kernel<5><<<NT64, 256, 0, stream>>>(
                h, nodeThi + (size_t)(l + 1) * 16384, nodeTlo + (size_t)(l + 1) * 16384,
                nullptr, nullptr, hxb, NT64);
        } else {
            gemv64_kernel<4><<<NT64, 256, 0, stream>>>(
                h, nodeThi + (size_t)18 * 16384, nodeTlo + (size_t)18 * 16384,
                l1b, h1, nullptr, NT64);
        }
    }

    hipMemsetAsync(gsum, 0, (size_t)(NGRAPH*HD + NGRAPH) * 4, stream);
    pool_kernel<<<256, HD, 0, stream>>>(h1, batch, gsum, gcnt, N);
    finalize_kernel<<<NGRAPH, HD, 0, stream>>>(gsum, gcnt, l1w, l1b, l2w, l2b,
                                               (float*)d_out);
}

// Round 11
// 455.247 us; speedup vs baseline: 1.5897x; 1.1521x over previous
//
#include <hip/hip_runtime.h>
#include <hip/hip_bf16.h>

#define HD 128
#define NGAUSS 50
#define NLAYER 6
#define NGRAPH 16
#define NCLS 97
#define NTAB2 8192
#define WMAX 12.0f

typedef __attribute__((ext_vector_type(8))) short bf16x8;
typedef __attribute__((ext_vector_type(4))) float f32x4;
typedef __attribute__((ext_vector_type(8))) ushort u16x8;
typedef __attribute__((ext_vector_type(4))) ushort u16x4;

__device__ __forceinline__ float ssp_f(float x) {
    float e = __expf(-fabsf(x));
    return fmaxf(x, 0.0f) + __logf(0.5f + 0.5f * e);
}
__device__ __forceinline__ ushort f2bf(float f) {   // RNE f32->bf16
    uint u = __float_as_uint(f);
    return (ushort)((u + 0x7FFFu + ((u >> 16) & 1u)) >> 16);
}
__device__ __forceinline__ float bf2f(ushort s) {
    return __uint_as_float(((uint)s) << 16);
}

// ================= CSR build =================
__global__ void hist_kernel(const int* __restrict__ col, int* __restrict__ deg, int E) {
    int e = blockIdx.x * blockDim.x + threadIdx.x;
    if (e < E) atomicAdd(&deg[col[e]], 1);
}

__global__ void scan1_kernel(const int* __restrict__ deg, int* __restrict__ rowp,
                             int* __restrict__ bsum, int N) {
    __shared__ int sm[256];
    const int t = threadIdx.x, i = blockIdx.x * 256 + t;
    int v = (i < N) ? deg[i] : 0;
    sm[t] = v;
    __syncthreads();
    for (int off = 1; off < 256; off <<= 1) {
        int x = sm[t];
        int a = (t >= off) ? sm[t - off] : 0;
        __syncthreads();
        sm[t] = x + a;
        __syncthreads();
    }
    if (i < N) rowp[i] = sm[t] - v;
    if (t == 255) bsum[blockIdx.x] = sm[255];
}
__global__ void scan2_kernel(const int* __restrict__ bsum, int* __restrict__ boff,
                             int NB, int* __restrict__ rowpN) {
    __shared__ int sm[256];
    const int t = threadIdx.x;
    int v = (t < NB) ? bsum[t] : 0;
    sm[t] = v;
    __syncthreads();
    for (int off = 1; off < 256; off <<= 1) {
        int x = sm[t];
        int a = (t >= off) ? sm[t - off] : 0;
        __syncthreads();
        sm[t] = x + a;
        __syncthreads();
    }
    if (t < NB) boff[t] = sm[t] - v;
    if (t == 255) *rowpN = sm[255];
}
__global__ void scan3_kernel(int* __restrict__ rowp, const int* __restrict__ boff,
                             int* __restrict__ cursor, int N) {
    int i = blockIdx.x * blockDim.x + threadIdx.x;
    if (i < N) {
        int r = rowp[i] + boff[i >> 8];
        rowp[i] = r;
        cursor[i] = r;
    }
}

// per-slot metadata (8 B): word0 = row | (nearest_tab_idx<<16); word1 = cenv (f32 bits)
__global__ void fill_kernel(const int* __restrict__ row, const int* __restrict__ col,
                            const float* __restrict__ pos, int* __restrict__ cursor,
                            uint2* __restrict__ meta, int E) {
    int e = blockIdx.x * blockDim.x + threadIdx.x;
    if (e >= E) return;
    int c = col[e], r = row[e];
    int slot = atomicAdd(&cursor[c], 1);
    float dx = pos[r*3+0] - pos[c*3+0];
    float dy = pos[r*3+1] - pos[c*3+1];
    float dz = pos[r*3+2] - pos[c*3+2];
    float w = sqrtf(dx*dx + dy*dy + dz*dz);
    float cenv = 0.5f * (cosf(w * 0.31415926535897931f) + 1.0f);
    const float invDW = (float)(NTAB2 - 1) / WMAX;
    int i = (int)(w * invDW + 0.5f);     // nearest neighbor
    i = min(i, NTAB2 - 1);
    uint w0 = ((uint)r) | (((uint)i) << 16);
    meta[slot] = make_uint2(w0, __float_as_uint(cenv));
}

// ================= weight prep =================
__global__ void prep_kernel(const float* __restrict__ m1w, const float* __restrict__ c1w,
                            const float* __restrict__ c2w, const float* __restrict__ lw,
                            const float* __restrict__ l1w, const float* __restrict__ m2w,
                            ushort* __restrict__ m1T, ushort* __restrict__ nodeThi,
                            ushort* __restrict__ nodeTlo, ushort* __restrict__ m2T) {
    int idx = blockIdx.x * blockDim.x + threadIdx.x;
    const int S1 = 6*128*64, S2 = 19*128*128, S3 = 6*128*128;
    if (idx < S1) {
        int l = idx / 8192, r = idx % 8192, c = r / 64, k = r % 64;
        float v = (k < NGAUSS) ? m1w[(size_t)l*NGAUSS*128 + k*128 + c] : 0.0f;
        m1T[(size_t)l*8192 + c*64 + k] = f2bf(v);
    } else if (idx < S1 + S2) {
        int j = idx - S1;
        int m = j / 16384, r = j % 16384, c = r / 128, k = r % 128;
        const float* src;
        if (m < 6)       src = c1w + (size_t)m*16384;
        else if (m < 12) src = c2w + (size_t)(m-6)*16384;
        else if (m < 18) src = lw  + (size_t)(m-12)*16384;
        else             src = l1w;
        float v = src[k*128 + c];
        ushort hi = f2bf(v);
        nodeThi[(size_t)m*16384 + c*128 + k] = hi;
        nodeTlo[(size_t)m*16384 + c*128 + k] = f2bf(v - bf2f(hi));
    } else if (idx < S1 + S2 + S3) {
        int j = idx - S1 - S2;
        int l = j / 16384, r = j % 16384, c = r / 128, k = r % 128;
        m2T[(size_t)l*16384 + c*128 + k] = f2bf(m2w[(size_t)l*16384 + k*128 + c]);
    }
}

// ================= embedding =================
__global__ void embed_kernel(const float* __restrict__ x,
                             const float* __restrict__ emb_w, const float* __restrict__ emb_b,
                             float* __restrict__ h, int N) {
    int idx = blockIdx.x * blockDim.x + threadIdx.x;
    if (idx >= N * HD) return;
    int n = idx >> 7, t = idx & 127;
    float acc = emb_b[t];
    #pragma unroll
    for (int a = 0; a < 21; ++a) acc += x[n*21 + a] * emb_w[a*HD + t];
    h[idx] = acc;
}

// ========= filter table build (proven structure) — writes bf16 table directly ======
// grid = 6 layers x (NTAB2/128) tiles.
__global__ __launch_bounds__(256, 2) void buildtab_kernel(
        const ushort* __restrict__ m1T_all, const ushort* __restrict__ m2T_all,
        const float* __restrict__ m1b_all, const float* __restrict__ m2b_all,
        ushort* __restrict__ Tb6) {
    __shared__ ushort A1[128 * 64];
    __shared__ ushort B1[128 * 64];
    __shared__ ushort U [128 * 128];
    char* A1b = (char*)A1;
    char* B1b = (char*)B1;
    char* Ub  = (char*)U;
    const int tid  = threadIdx.x;
    const int lane = tid & 63;
    const int wave = tid >> 6;
    const int l15  = lane & 15;
    const int kgrp = (lane >> 4) * 8;
    const int rbase = wave * 32;
    const int NTILES = NTAB2 / 128;
    const int layer = blockIdx.x / NTILES;
    const int mt    = blockIdx.x % NTILES;
    const ushort* m1T = m1T_all + (size_t)layer * 8192;
    const ushort* m2T = m2T_all + (size_t)layer * 16384;
    const float*  m1b = m1b_all + layer * HD;
    const float*  m2b = m2b_all + layer * HD;

    #pragma unroll
    for (int p = 0; p < 4; ++p) {
        int rr = p * 32 + (tid >> 3);
        int k8 = (tid & 7) * 8;
        u16x8 v = *reinterpret_cast<const u16x8*>(&m1T[(size_t)rr * 64 + k8]);
        *reinterpret_cast<u16x8*>(&B1b[rr*128 + ((2*k8) ^ ((rr & 7) << 4))]) = v;
    }

    float b1c[8], b2c[8];
    #pragma unroll
    for (int cb = 0; cb < 8; ++cb) { b1c[cb] = m1b[cb*16 + l15]; b2c[cb] = m2b[cb*16 + l15]; }

    const float step = 10.0f / 49.0f;
    const float coeff = -0.5f / (step * step);
    const float DW = WMAX / (float)(NTAB2 - 1);

    #pragma unroll
    for (int p = 0; p < 4; ++p) {
        int rr = p * 32 + (tid >> 3);
        int k8 = (tid & 7) * 8;
        float w = (float)(mt*128 + rr) * DW;
        u16x8 v;
        #pragma unroll
        for (int j = 0; j < 8; ++j) {
            int k = k8 + j;
            float d = w - (float)k * step;
            float g = (k < NGAUSS) ? __expf(coeff * d * d) : 0.0f;
            v[j] = f2bf(g);
        }
        *reinterpret_cast<u16x8*>(&A1b[rr*128 + ((2*k8) ^ ((rr & 7) << 4))]) = v;
    }
    __syncthreads();

    f32x4 acc1[2][8];
    #pragma unroll
    for (int i = 0; i < 2; ++i)
        #pragma unroll
        for (int j = 0; j < 8; ++j) { acc1[i][j].x=0.f; acc1[i][j].y=0.f; acc1[i][j].z=0.f; acc1[i][j].w=0.f; }
    #pragma unroll
    for (int ks = 0; ks < 2; ++ks) {
        int k = ks*32 + kgrp;
        bf16x8 af[2];
        #pragma unroll
        for (int rt = 0; rt < 2; ++rt) {
            int r = rbase + rt*16 + l15;
            af[rt] = *reinterpret_cast<const bf16x8*>(&A1b[r*128 + ((2*k) ^ ((r & 7) << 4))]);
        }
        #pragma unroll
        for (int cb = 0; cb < 8; ++cb) {
            int c = cb*16 + l15;
            bf16x8 bv = *reinterpret_cast<const bf16x8*>(&B1b[c*128 + ((2*k) ^ ((c & 7) << 4))]);
            acc1[0][cb] = __builtin_amdgcn_mfma_f32_16x16x32_bf16(af[0], bv, acc1[0][cb], 0, 0, 0);
            acc1[1][cb] = __builtin_amdgcn_mfma_f32_16x16x32_bf16(af[1], bv, acc1[1][cb], 0, 0, 0);
        }
    }
    #pragma unroll
    for (int rt = 0; rt < 2; ++rt) {
        #pragma unroll
        for (int cb = 0; cb < 8; ++cb) {
            int c = cb*16 + l15;
            #pragma unroll
            for (int i = 0; i < 4; ++i) {
                int rrow = rbase + rt*16 + (lane >> 4)*4 + i;
                ushort us = f2bf(ssp_f(acc1[rt][cb][i] + b1c[cb]));
                *reinterpret_cast<ushort*>(&Ub[rrow*256 + ((2*c) ^ ((rrow & 7) << 4))]) = us;
            }
        }
    }
    __syncthreads();

    f32x4 acc2[2][8];
    #pragma unroll
    for (int i = 0; i < 2; ++i)
        #pragma unroll
        for (int j = 0; j < 8; ++j) { acc2[i][j].x=0.f; acc2[i][j].y=0.f; acc2[i][j].z=0.f; acc2[i][j].w=0.f; }
    #pragma unroll
    for (int kh = 0; kh < 2; ++kh) {
        if (kh) __syncthreads();
        #pragma unroll
        for (int p = 0; p < 4; ++p) {
            int rr = p * 32 + (tid >> 3);
            int kk = (tid & 7) * 8;
            u16x8 v = *reinterpret_cast<const u16x8*>(&m2T[(size_t)rr*128 + kh*64 + kk]);
            *reinterpret_cast<u16x8*>(&A1b[rr*128 + ((2*kk) ^ ((rr & 7) << 4))]) = v;
        }
        __syncthreads();
        #pragma unroll
        for (int ks2 = 0; ks2 < 2; ++ks2) {
            int ku = kh*64 + ks2*32 + kgrp;
            int kb = ks2*32 + kgrp;
            bf16x8 af[2];
            #pragma unroll
            for (int rt = 0; rt < 2; ++rt) {
                int r = rbase + rt*16 + l15;
                af[rt] = *reinterpret_cast<const bf16x8*>(&Ub[r*256 + ((2*ku) ^ ((r & 7) << 4))]);
            }
            #pragma unroll
            for (int cb = 0; cb < 8; ++cb) {
                int c = cb*16 + l15;
                bf16x8 bv = *reinterpret_cast<const bf16x8*>(&A1b[c*128 + ((2*kb) ^ ((c & 7) << 4))]);
                acc2[0][cb] = __builtin_amdgcn_mfma_f32_16x16x32_bf16(af[0], bv, acc2[0][cb], 0, 0, 0);
                acc2[1][cb] = __builtin_amdgcn_mfma_f32_16x16x32_bf16(af[1], bv, acc2[1][cb], 0, 0, 0);
            }
        }
    }

    #pragma unroll
    for (int rt = 0; rt < 2; ++rt) {
        #pragma unroll
        for (int cb = 0; cb < 8; ++cb) {
            int c = cb*16 + l15;
            #pragma unroll
            for (int i = 0; i < 4; ++i) {
                int rrow = rbase + rt*16 + (lane >> 4)*4 + i;
                Tb6[((size_t)layer*NTAB2 + mt*128 + rrow) * HD + c] = f2bf(acc2[rt][cb][i] + b2c[cb]);
            }
        }
    }
}

// ============ persistent-weight 64-row GEMV: out = EPI(h @ (Bhi+Blo)) ============
template<int EPI>
__global__ __launch_bounds__(256) void gemv64_kernel(
        const float* __restrict__ A, const ushort* __restrict__ BThi,
        const ushort* __restrict__ BTlo, const float* __restrict__ bias,
        float* __restrict__ fdst, ushort* __restrict__ bdst, int mtiles) {
    __shared__ ushort Bw[128 * 256];   // 64KB
    __shared__ ushort A_[64 * 128];    // 16KB
    char* Bwb = (char*)Bw;
    char* Ab  = (char*)A_;
    const int tid  = threadIdx.x;
    const int lane = tid & 63;
    const int wave = tid >> 6;
    const int l15  = lane & 15;
    const int kgrp = (lane >> 4) * 8;
    const int rbase = wave * 16;

    #pragma unroll
    for (int p = 0; p < 16; ++p) {
        int idx = p * 256 + tid;
        int c = idx >> 5;
        int k8 = (idx & 31) * 8;
        const ushort* src = (k8 < 128) ? BThi : BTlo;
        u16x8 v = *reinterpret_cast<const u16x8*>(&src[(size_t)c*128 + (k8 & 127)]);
        *reinterpret_cast<u16x8*>(&Bwb[c*512 + ((2*k8) ^ ((c & 7) << 4))]) = v;
    }
    float bt[8];
    if (EPI == 4) {
        #pragma unroll
        for (int cb = 0; cb < 8; ++cb) bt[cb] = bias[cb*16 + l15];
    }
    __syncthreads();

    for (int mt = blockIdx.x; mt < mtiles; mt += gridDim.x) {
        #pragma unroll
        for (int p = 0; p < 8; ++p) {
            int rr = p * 8 + (tid >> 5);
            int k4 = (tid & 31) * 4;
            f32x4 v = *reinterpret_cast<const f32x4*>(&A[(size_t)(mt*64 + rr)*HD + k4]);
            u16x4 b;
            b.x = f2bf(v.x); b.y = f2bf(v.y); b.z = f2bf(v.z); b.w = f2bf(v.w);
            *reinterpret_cast<u16x4*>(&Ab[rr*256 + ((2*k4) ^ ((rr & 7) << 4))]) = b;
        }
        __syncthreads();

        bf16x8 af[4];
        {
            int r = rbase + l15;
            #pragma unroll
            for (int q = 0; q < 4; ++q)
                af[q] = *reinterpret_cast<const bf16x8*>(&Ab[r*256 + ((2*(q*32 + kgrp)) ^ ((r & 7) << 4))]);
        }
        f32x4 acc[8];
        #pragma unroll
        for (int j = 0; j < 8; ++j) { acc[j].x=0.f; acc[j].y=0.f; acc[j].z=0.f; acc[j].w=0.f; }
        #pragma unroll
        for (int ks = 0; ks < 8; ++ks) {
            int kB = ks*32 + kgrp;
            #pragma unroll
            for (int cb = 0; cb < 8; ++cb) {
                int c = cb*16 + l15;
                bf16x8 bv = *reinterpret_cast<const bf16x8*>(&Bwb[c*512 + ((2*kB) ^ ((c & 7) << 4))]);
                acc[cb] = __builtin_amdgcn_mfma_f32_16x16x32_bf16(af[ks & 3], bv, acc[cb], 0, 0, 0);
            }
        }

        #pragma unroll
        for (int cb = 0; cb < 8; ++cb) {
            int c = cb*16 + l15;
            #pragma unroll
            for (int i = 0; i < 4; ++i) {
                int row = mt*64 + rbase + (lane >> 4)*4 + i;
                size_t off = (size_t)row * HD + c;
                if (EPI == 4) fdst[off] = fmaxf(acc[cb][i] + bt[cb], 0.0f);
                else          bdst[off] = f2bf(acc[cb][i]);
            }
        }
        __syncthreads();
    }
}

// ======== persistent-weight fused node block (32-row tiles, 512 threads) ========
__global__ __launch_bounds__(512, 1) void nodefused_kernel(
        const ushort* __restrict__ aggb,
        const ushort* __restrict__ c2hi, const ushort* __restrict__ c2lo,
        const float* __restrict__ c2b,
        const ushort* __restrict__ lwhi, const ushort* __restrict__ lwlo,
        const float* __restrict__ lb,
        float* __restrict__ h, int mtiles) {
    __shared__ ushort W1[128 * 256];   // 64KB
    __shared__ ushort W2[128 * 256];   // 64KB
    __shared__ ushort BUF[32 * 128];   // 8KB (A, then U)
    char* W1b = (char*)W1;
    char* W2b = (char*)W2;
    char* Bu  = (char*)BUF;
    const int tid  = threadIdx.x;
    const int lane = tid & 63;
    const int wave = tid >> 6;
    const int l15  = lane & 15;
    const int kgrp = (lane >> 4) * 8;
    const int wr = (wave & 1) * 16;
    const int wc = (wave >> 1) * 2;

    #pragma unroll
    for (int p = 0; p < 8; ++p) {
        int idx = p * 512 + tid;
        int c = idx >> 5;
        int k8 = (idx & 31) * 8;
        const ushort* s1 = (k8 < 128) ? c2hi : c2lo;
        u16x8 v1 = *reinterpret_cast<const u16x8*>(&s1[(size_t)c*128 + (k8 & 127)]);
        *reinterpret_cast<u16x8*>(&W1b[c*512 + ((2*k8) ^ ((c & 7) << 4))]) = v1;
        const ushort* s2 = (k8 < 128) ? lwhi : lwlo;
        u16x8 v2 = *reinterpret_cast<const u16x8*>(&s2[(size_t)c*128 + (k8 & 127)]);
        *reinterpret_cast<u16x8*>(&W2b[c*512 + ((2*k8) ^ ((c & 7) << 4))]) = v2;
    }
    float b1c[2], b2c[2];
    #pragma unroll
    for (int cb = 0; cb < 2; ++cb) {
        int c = (wc + cb)*16 + l15;
        b1c[cb] = c2b[c];
        b2c[cb] = lb[c];
    }
    __syncthreads();

    for (int mt = blockIdx.x; mt < mtiles; mt += gridDim.x) {
        {
            int rr = tid >> 4;
            int k8 = (tid & 15) * 8;
            u16x8 v = *reinterpret_cast<const u16x8*>(&aggb[(size_t)(mt*32 + rr)*HD + k8]);
            *reinterpret_cast<u16x8*>(&Bu[rr*256 + ((2*k8) ^ ((rr & 7) << 4))]) = v;
        }
        float hp[2][4];
        #pragma unroll
        for (int cb = 0; cb < 2; ++cb) {
            int c = (wc + cb)*16 + l15;
            #pragma unroll
            for (int i = 0; i < 4; ++i) {
                int row = mt*32 + wr + (lane >> 4)*4 + i;
                hp[cb][i] = h[(size_t)row * HD + c];
            }
        }
        __syncthreads();

        bf16x8 af[4];
        {
            int r = wr + l15;
            #pragma unroll
            for (int q = 0; q < 4; ++q)
                af[q] = *reinterpret_cast<const bf16x8*>(&Bu[r*256 + ((2*(q*32 + kgrp)) ^ ((r & 7) << 4))]);
        }
        f32x4 acc[2];
        #pragma unroll
        for (int j = 0; j < 2; ++j) { acc[j].x=0.f; acc[j].y=0.f; acc[j].z=0.f; acc[j].w=0.f; }
        #pragma unroll
        for (int ks = 0; ks < 8; ++ks) {
            int kB = ks*32 + kgrp;
            #pragma unroll
            for (int cb = 0; cb < 2; ++cb) {
                int c = (wc + cb)*16 + l15;
                bf16x8 bv = *reinterpret_cast<const bf16x8*>(&W1b[c*512 + ((2*kB) ^ ((c & 7) << 4))]);
                acc[cb] = __builtin_amdgcn_mfma_f32_16x16x32_bf16(af[ks & 3], bv, acc[cb], 0, 0, 0);
            }
        }
        __syncthreads();

        #pragma unroll
        for (int cb = 0; cb < 2; ++cb) {
            int c = (wc + cb)*16 + l15;
            #pragma unroll
            for (int i = 0; i < 4; ++i) {
                int rrow = wr + (lane >> 4)*4 + i;
                ushort us = f2bf(ssp_f(acc[cb][i] + b1c[cb]));
                *reinterpret_cast<ushort*>(&Bu[rrow*256 + ((2*c) ^ ((rrow & 7) << 4))]) = us;
            }
        }
        __syncthreads();

        {
            int r = wr + l15;
            #pragma unroll
            for (int q = 0; q < 4; ++q)
                af[q] = *reinterpret_cast<const bf16x8*>(&Bu[r*256 + ((2*(q*32 + kgrp)) ^ ((r & 7) << 4))]);
        }
        #pragma unroll
        for (int j = 0; j < 2; ++j) { acc[j].x=0.f; acc[j].y=0.f; acc[j].z=0.f; acc[j].w=0.f; }
        #pragma unroll
        for (int ks = 0; ks < 8; ++ks) {
            int kB = ks*32 + kgrp;
            #pragma unroll
            for (int cb = 0; cb < 2; ++cb) {
                int c = (wc + cb)*16 + l15;
                bf16x8 bv = *reinterpret_cast<const bf16x8*>(&W2b[c*512 + ((2*kB) ^ ((c & 7) << 4))]);
                acc[cb] = __builtin_amdgcn_mfma_f32_16x16x32_bf16(af[ks & 3], bv, acc[cb], 0, 0, 0);
            }
        }
        #pragma unroll
        for (int cb = 0; cb < 2; ++cb) {
            int c = (wc + cb)*16 + l15;
            #pragma unroll
            for (int i = 0; i < 4; ++i) {
                int row = mt*32 + wr + (lane >> 4)*4 + i;
                h[(size_t)row * HD + c] = hp[cb][i] + acc[cb][i] + b2c[cb];
            }
        }
        __syncthreads();
    }
}

// ========= fused gather-NN-segment-sum (8-slot unrolled, bf16 table) =========
// agg[n][t] = sum_s Tb[idx_s][t] * cenv_s * hx[row_s][t]
__global__ __launch_bounds__(256) void gathersum_kernel(
        const ushort* __restrict__ Tb, const uint2* __restrict__ meta,
        const int* __restrict__ rowp, const ushort* __restrict__ hxb,
        ushort* __restrict__ aggb, int N) {
    const int lane = threadIdx.x & 63;
    const int n = blockIdx.x * 4 + (threadIdx.x >> 6);
    if (n >= N) return;
    const int c0 = lane * 2;
    const int s0 = rowp[n], s1 = rowp[n + 1];
    float al[4] = {0.f, 0.f, 0.f, 0.f};
    float ah[4] = {0.f, 0.f, 0.f, 0.f};
    int s = s0;
    for (; s + 8 <= s1; s += 8) {
        uint2 m[8];
        uint tv[8], hv[8];
        #pragma unroll
        for (int k = 0; k < 8; ++k) m[k] = meta[s + k];
        #pragma unroll
        for (int k = 0; k < 8; ++k) {
            tv[k] = *reinterpret_cast<const uint*>(&Tb[(size_t)(m[k].x >> 16) * HD + c0]);
            hv[k] = *reinterpret_cast<const uint*>(&hxb[(size_t)(m[k].x & 0xFFFFu) * HD + c0]);
        }
        #pragma unroll
        for (int k = 0; k < 8; ++k) {
            float cv = __uint_as_float(m[k].y);
            float glo = __uint_as_float(tv[k] << 16) * cv;
            float ghi = __uint_as_float(tv[k] & 0xFFFF0000u) * cv;
            al[k & 3] += glo * __uint_as_float(hv[k] << 16);
            ah[k & 3] += ghi * __uint_as_float(hv[k] & 0xFFFF0000u);
        }
    }
    for (; s < s1; ++s) {
        uint2 m0 = meta[s];
        uint tv = *reinterpret_cast<const uint*>(&Tb[(size_t)(m0.x >> 16) * HD + c0]);
        uint hv = *reinterpret_cast<const uint*>(&hxb[(size_t)(m0.x & 0xFFFFu) * HD + c0]);
        float cv = __uint_as_float(m0.y);
        al[0] += __uint_as_float(tv << 16) * cv * __uint_as_float(hv << 16);
        ah[0] += __uint_as_float(tv & 0xFFFF0000u) * cv * __uint_as_float(hv & 0xFFFF0000u);
    }
    float lo = (al[0] + al[1]) + (al[2] + al[3]);
    float hi = (ah[0] + ah[1]) + (ah[2] + ah[3]);
    uint out = ((uint)f2bf(lo)) | (((uint)f2bf(hi)) << 16);
    *reinterpret_cast<uint*>(&aggb[(size_t)n * HD + c0]) = out;
}

// ================= mean pool =================
__global__ void pool_kernel(const float* __restrict__ h1, const int* __restrict__ batch,
                            float* __restrict__ gsum, float* __restrict__ gcnt, int N) {
    __shared__ float pool[NGRAPH][HD];
    __shared__ float cnt[NGRAPH];
    const int t = threadIdx.x;
    #pragma unroll
    for (int g = 0; g < NGRAPH; ++g) pool[g][t] = 0.0f;
    if (t < NGRAPH) cnt[t] = 0.0f;
    __syncthreads();
    int chunk = (N + gridDim.x - 1) / gridDim.x;
    int n0 = blockIdx.x * chunk, n1 = min(N, n0 + chunk);
    for (int n = n0; n < n1; ++n) {
        int b = batch[n];
        pool[b][t] += h1[(size_t)n * HD + t];
        if (t == 0) cnt[b] += 1.0f;
    }
    __syncthreads();
    #pragma unroll
    for (int g = 0; g < NGRAPH; ++g) atomicAdd(&gsum[g*HD + t], pool[g][t]);
    if (t < NGRAPH) atomicAdd(&gcnt[t], cnt[t]);
}

// ================= head =================
__global__ void finalize_kernel(const float* __restrict__ gsum, const float* __restrict__ gcnt,
                                const float* __restrict__ l1w, const float* __restrict__ l1b,
                                const float* __restrict__ l2w, const float* __restrict__ l2b,
                                float* __restrict__ d_out) {
    __shared__ float ge[HD];
    __shared__ float h2[HD];
    const int g = blockIdx.x, t = threadIdx.x;
    float cnt = fmaxf(gcnt[g], 1.0f);
    float v = gsum[g*HD + t] / cnt;
    d_out[g*HD + t] = v;
    ge[t] = v;
    __syncthreads();
    float acc = l1b[t];
    #pragma unroll 8
    for (int k = 0; k < HD; ++k) acc += ge[k] * l1w[k*HD + t];
    h2[t] = fmaxf(acc, 0.0f);
    __syncthreads();
    if (t < NCLS) {
        float o = l2b[t];
        #pragma unroll 8
        for (int k = 0; k < HD; ++k) o += h2[k] * l2w[k*NCLS + t];
        d_out[NGRAPH*HD + g*NCLS + t] = o;
    }
}

extern "C" void kernel_launch(void* const* d_in, const int* in_sizes, int n_in,
                              void* d_out, int out_size, void* d_ws, size_t ws_size,
                              hipStream_t stream) {
    const float* x     = (const float*)d_in[0];
    const float* pos   = (const float*)d_in[1];
    const int*   eidx  = (const int*)d_in[2];
    const int*   batch = (const int*)d_in[3];
    const float* emb_w = (const float*)d_in[4];
    const float* emb_b = (const float*)d_in[5];
    const float* m1w   = (const float*)d_in[6];
    const float* m1b   = (const float*)d_in[7];
    const float* m2w   = (const float*)d_in[8];
    const float* m2b   = (const float*)d_in[9];
    const float* c1w   = (const float*)d_in[10];
    const float* c2w   = (const float*)d_in[11];
    const float* c2b   = (const float*)d_in[12];
    const float* lw    = (const float*)d_in[13];
    const float* lb    = (const float*)d_in[14];
    const float* l1w   = (const float*)d_in[15];
    const float* l1b   = (const float*)d_in[16];
    const float* l2w   = (const float*)d_in[17];
    const float* l2b   = (const float*)d_in[18];

    const int N = in_sizes[0] / 21;          // 20000
    const int E = in_sizes[2] / 2;           // 640000
    const int* row = eidx;
    const int* col = eidx + E;
    const int NT64 = (N + 63) / 64;          // 313
    const int NT32 = (N + 31) / 32;          // 625
    const int NB   = (N + 255) / 256;        // 79
    const int Npad = NT64 * 64 + 64;

    size_t off = 0;
    char* base = (char*)d_ws;
    auto alloc = [&](size_t bytes) -> void* {
        off = (off + 255) & ~(size_t)255;
        void* p = base + off;
        off += bytes;
        return p;
    };
    int*    deg     = (int*)alloc((size_t)N * 4);
    int*    cursor  = (int*)alloc((size_t)N * 4);
    int*    rowp    = (int*)alloc((size_t)(N + 1) * 4);
    int*    bsum    = (int*)alloc(512 * 4);
    int*    boff    = (int*)alloc(512 * 4);
    uint2*  meta    = (uint2*)alloc((size_t)E * 8);
    float*  h       = (float*)alloc((size_t)Npad * HD * 4);
    ushort* hxb     = (ushort*)alloc((size_t)Npad * HD * 2);
    ushort* aggb    = (ushort*)alloc((size_t)Npad * HD * 2);
    float*  h1      = (float*)alloc((size_t)Npad * HD * 4);
    ushort* Tb6     = (ushort*)alloc((size_t)6 * NTAB2 * HD * 2);
    ushort* m1T     = (ushort*)alloc((size_t)6 * 128 * 64 * 2);
    ushort* nodeThi = (ushort*)alloc((size_t)19 * 128 * 128 * 2);
    ushort* nodeTlo = (ushort*)alloc((size_t)19 * 128 * 128 * 2);
    ushort* m2T     = (ushort*)alloc((size_t)6 * 128 * 128 * 2);
    float*  gsum    = (float*)alloc((size_t)NGRAPH * HD * 4);
    float*  gcnt    = (float*)alloc((size_t)NGRAPH * 4);

    // ---- one-time: weight prep + CSR + filter tables ----
    prep_kernel<<<1792, 256, 0, stream>>>(m1w, c1w, c2w, lw, l1w, m2w,
                                          m1T, nodeThi, nodeTlo, m2T);
    hipMemsetAsync(deg, 0, (size_t)N * 4, stream);
    hist_kernel<<<(E + 255)/256, 256, 0, stream>>>(col, deg, E);
    scan1_kernel<<<NB, 256, 0, stream>>>(deg, rowp, bsum, N);
    scan2_kernel<<<1, 256, 0, stream>>>(bsum, boff, NB, rowp + N);
    scan3_kernel<<<NB, 256, 0, stream>>>(rowp, boff, cursor, N);
    fill_kernel<<<(E + 255)/256, 256, 0, stream>>>(row, col, pos, cursor, meta, E);
    buildtab_kernel<<<6 * (NTAB2/128), 256, 0, stream>>>(m1T, m2T, m1b, m2b, Tb6);
    embed_kernel<<<(N*HD + 255)/256, 256, 0, stream>>>(x, emb_w, emb_b, h, N);

    // hxb for layer 0
    gemv64_kernel<5><<<NT64, 256, 0, stream>>>(h, nodeThi, nodeTlo, nullptr,
                                               nullptr, hxb, NT64);

    for (int l = 0; l < NLAYER; ++l) {
        const ushort* c2Thi = nodeThi + (size_t)(6 + l) * 16384;
        const ushort* c2Tlo = nodeTlo + (size_t)(6 + l) * 16384;
        const ushort* lThi  = nodeThi + (size_t)(12 + l) * 16384;
        const ushort* lTlo  = nodeTlo + (size_t)(12 + l) * 16384;

        gathersum_kernel<<<(N + 3)/4, 256, 0, stream>>>(
            Tb6 + (size_t)l * NTAB2 * HD, meta, rowp, hxb, aggb, N);

        nodefused_kernel<<<256, 512, 0, stream>>>(
            aggb, c2Thi, c2Tlo, c2b + l*HD, lThi, lTlo, lb + l*HD, h, NT32);

        if (l < NLAYER - 1) {
            gemv64_kernel<5><<<NT64, 256, 0, stream>>>(
                h, nodeThi + (size_t)(l + 1) * 16384, nodeTlo + (size_t)(l + 1) * 16384,
                nullptr, nullptr, hxb, NT64);
        } else {
            gemv64_kernel<4><<<NT64, 256, 0, stream>>>(
                h, nodeThi + (size_t)18 * 16384, nodeTlo + (size_t)18 * 16384,
                l1b, h1, nullptr, NT64);
        }
    }

    hipMemsetAsync(gsum, 0, (size_t)(NGRAPH*HD + NGRAPH) * 4, stream);
    pool_kernel<<<256, HD, 0, stream>>>(h1, batch, gsum, gcnt, N);
    finalize_kernel<<<NGRAPH, HD, 0, stream>>>(gsum, gcnt, l1w, l1b, l2w, l2b,
                                               (float*)d_out);
}